// Round 12
// baseline (236.153 us; speedup 1.0000x reference)
//
#include <hip/hip_runtime.h>
#include <hip/hip_bf16.h>

typedef __attribute__((ext_vector_type(8))) short short8b;
typedef __attribute__((ext_vector_type(4))) float float4v;

static __device__ __forceinline__ unsigned short f2bf_bits(float f) {
  union { __hip_bfloat16 h; unsigned short u; } c;
  c.h = __float2bfloat16(f);
  return c.u;
}

static __device__ __forceinline__ short8b cvt8(const float* s) {
  union { short8b v; unsigned short us[8]; } o;
#pragma unroll
  for (int i = 0; i < 8; ++i) o.us[i] = f2bf_bits(s[i]);
  return o.v;
}

// ---------------------------------------------------------------------------
// K0: X f32 -> bf16 (proj_gemm re-reads X 20x, so pre-cast pays)
// ---------------------------------------------------------------------------
__global__ __launch_bounds__(256) void cast_X(const float* __restrict__ src,
                                              __hip_bfloat16* __restrict__ dst) {
  int i = blockIdx.x * 256 + threadIdx.x;      // 262144 float4 groups
  float4 v = reinterpret_cast<const float4*>(src)[i];
  union { ushort4 u; __hip_bfloat16 h[4]; } o;
  o.h[0] = __float2bfloat16(v.x); o.h[1] = __float2bfloat16(v.y);
  o.h[2] = __float2bfloat16(v.z); o.h[3] = __float2bfloat16(v.w);
  reinterpret_cast<ushort4*>(dst)[i] = o.u;
}

// ---------------------------------------------------------------------------
// K1: projection GEMM (R9 version). C(4096 x 1280) = Xb @ W^T, 128x64 tiles.
// W f32 converted in staging. Q-scaling includes log2(e). Epilogue scatters
// per-head: Qs,K,Qf,Kf : [bh][2048][32]    V -> Vt : [bh][32][2048]
// ---------------------------------------------------------------------------
__global__ __launch_bounds__(256) void proj_gemm(
    const __hip_bfloat16* __restrict__ Xb, const float* __restrict__ W1,
    const float* __restrict__ W2,
    const float* __restrict__ bias, const float* __restrict__ bias_s,
    __hip_bfloat16* __restrict__ Qs, __hip_bfloat16* __restrict__ Kg,
    __hip_bfloat16* __restrict__ Vt, __hip_bfloat16* __restrict__ Qf,
    __hip_bfloat16* __restrict__ Kf) {
    __shared__ __hip_bfloat16 At[128][40];
    __shared__ __hip_bfloat16 Bt[64][40];
    const int tid = threadIdx.x;
    const int lane = tid & 63, w = tid >> 6;
    const int ln = lane & 15, kg = lane >> 4;
    const int wr = w >> 1, wc = w & 1;
    const int rowBase = blockIdx.y * 128;
    const int colBase = blockIdx.x * 64;
    const float* Wsrc = (colBase < 768) ? (W1 + (size_t)colBase * 256)
                                        : (W2 + (size_t)(colBase - 768) * 256);
    float4v acc[4][2] = {};

    for (int kt = 0; kt < 8; ++kt) {
        int cid = tid;
#pragma unroll
        for (int p = 0; p < 2; ++p, cid += 256) {
            int row = cid >> 2, c = cid & 3;
            *(short8b*)&At[row][c * 8] =
                *(const short8b*)&Xb[(size_t)(rowBase + row) * 256 + kt * 32 + c * 8];
        }
        {
            int row = tid >> 2, c = tid & 3;
            float fb[8];
            *(float4*)&fb[0] = *(const float4*)&Wsrc[(size_t)row * 256 + kt * 32 + c * 8];
            *(float4*)&fb[4] = *(const float4*)&Wsrc[(size_t)row * 256 + kt * 32 + c * 8 + 4];
            *(short8b*)&Bt[row][c * 8] = cvt8(fb);
        }
        __syncthreads();
        short8b a[4], b[2];
#pragma unroll
        for (int mi = 0; mi < 4; ++mi) a[mi] = *(const short8b*)&At[wr * 64 + mi * 16 + ln][kg * 8];
#pragma unroll
        for (int nj = 0; nj < 2; ++nj) b[nj] = *(const short8b*)&Bt[wc * 32 + nj * 16 + ln][kg * 8];
#pragma unroll
        for (int mi = 0; mi < 4; ++mi)
#pragma unroll
            for (int nj = 0; nj < 2; ++nj)
                acc[mi][nj] = __builtin_amdgcn_mfma_f32_16x16x32_bf16(a[mi], b[nj], acc[mi][nj], 0, 0, 0);
        __syncthreads();
    }

    const float scaling = 0.17677669529663687f * 1.4426950408889634f;  // 32^-0.5 * log2(e)
#pragma unroll
    for (int mi = 0; mi < 4; ++mi) {
#pragma unroll
        for (int nj = 0; nj < 2; ++nj) {
            int j = colBase + wc * 32 + nj * 16 + ln;
            float bj = (j < 768) ? bias[j] : bias_s[j - 768];
#pragma unroll
            for (int r = 0; r < 4; ++r) {
                int row = rowBase + wr * 64 + mi * 16 + kg * 4 + r;
                float val = acc[mi][nj][r] + bj;
                int l = row >> 1, n = row & 1;
                if (j < 256) {
                    int h = j >> 5, d = j & 31;
                    Qs[(((n << 3) + h) * 2048 + l) * 32 + d] = __float2bfloat16(val * scaling);
                } else if (j < 512) {
                    int e = j - 256, h = e >> 5, d = e & 31;
                    Kg[(((n << 3) + h) * 2048 + l) * 32 + d] = __float2bfloat16(val);
                } else if (j < 768) {
                    int e = j - 512, h = e >> 5, d = e & 31;
                    Vt[(((n << 3) + h) * 32 + d) * 2048 + l] = __float2bfloat16(val);
                } else if (j < 1024) {
                    int e = j - 768, h = e >> 5, d = e & 31;
                    Qf[(((n << 3) + h) * 2048 + l) * 32 + d] = __float2bfloat16(val * scaling);
                } else {
                    int e = j - 1024, h = e >> 5, d = e & 31;
                    Kf[(((n << 3) + h) * 2048 + l) * 32 + d] = __float2bfloat16(val);
                }
            }
        }
    }
}

// ---------------------------------------------------------------------------
// K2: agent-aware flash attention, LDS-staged K/Ks + pipelined, splitS=4.
// grid 2048 = 8 xcd x {2 bh, 32 qg, 4 split}; block 256 thr = 4 waves x 16 q.
// THIS ROUND: V NOT staged (L2-resident per-head Vt, read direct) -> LDS
// drops 27.6 -> 18.4 KB; splitS=4 -> 8 blocks/CU of work; launch_bounds
// (256,6) caps VGPR ~84 (no spill) for ~6 blocks/CU residency.
// Per tile: K/Ks in LDS [64][36] with PV permutation applied at stage time,
// double-buffered, one barrier/tile, register prefetch of next K/Ks.
// Swapped QK^T, fixed softmax base m=0 (exp2 domain), in-lane P->A-frag, PV.
// Partial (O,l) -> PO/PL (f32).
// ---------------------------------------------------------------------------
__global__ __launch_bounds__(256, 6) void agent_attn(
    const __hip_bfloat16* __restrict__ Qs, const __hip_bfloat16* __restrict__ Kg,
    const __hip_bfloat16* __restrict__ Vt, const __hip_bfloat16* __restrict__ Qf,
    const __hip_bfloat16* __restrict__ Kf, const int* __restrict__ qid_g,
    const int* __restrict__ kid_g, float* __restrict__ PO, float* __restrict__ PL) {
  __shared__ __hip_bfloat16 Klds[2][64][36];
  __shared__ __hip_bfloat16 Kslds[2][64][36];

  const int tid = threadIdx.x;
  const int lane = tid & 63, w = tid >> 6;
  const int ln = lane & 15, kg = lane >> 4;

  const int flat = blockIdx.x;               // 2048 = 8 xcd * (2 bh | 32 qg | 4 split)
  const int slot = flat >> 3;
  const int bh = ((flat & 7) << 1) | (slot & 1);
  const int rest = slot >> 1;                // 0..127
  const int qg = rest & 31, split = rest >> 5;
  const int q0 = qg * 64 + w * 16;
  const int kbase = split * 512;

  const __hip_bfloat16* Qb  = Qs + (size_t)bh * 2048 * 32;
  const __hip_bfloat16* Qfb = Qf + (size_t)bh * 2048 * 32;
  const __hip_bfloat16* Kb  = Kg + (size_t)bh * 2048 * 32;
  const __hip_bfloat16* Ksb = Kf + (size_t)bh * 2048 * 32;
  const __hip_bfloat16* Vb  = Vt + (size_t)bh * 32 * 2048;

  // staging geometry (constant per thread)
  const int krho = tid >> 2, kseg = tid & 3;       // K/Ks: row [0,64), 4x8 bf16 segs
  const int ksub = krho >> 4, ki = krho & 15;
  // permuted global key for LDS row krho: g = (i>>2)*8 + (i&3) + off[sub]
  const int gK = ((ki >> 2) << 3) + (ki & 3) + ((ksub & 1) << 5) + ((ksub >> 1) << 2);

  // Q fragments (B-operand: row=q=ln, k=kg*8+j) + per-lane q identity
  short8b bQ  = *(const short8b*)&Qb [(q0 + ln) * 32 + kg * 8];
  short8b bQf = *(const short8b*)&Qfb[(q0 + ln) * 32 + kg * 8];
  const int qidq = qid_g[q0 + ln];

  float lacc = 0.f;                // per-lane partial softmax denominator
  float4v O0 = {0.f, 0.f, 0.f, 0.f}, O1 = {0.f, 0.f, 0.f, 0.f};

  // prologue: stage tile 0 into buffer 0
  {
    short8b rk = *(const short8b*)&Kb [(size_t)(kbase + gK) * 32 + kseg * 8];
    short8b rs = *(const short8b*)&Ksb[(size_t)(kbase + gK) * 32 + kseg * 8];
    *(short8b*)&Klds [0][krho][kseg * 8] = rk;
    *(short8b*)&Kslds[0][krho][kseg * 8] = rs;
  }
  __syncthreads();

  short8b rk, rs;
#pragma unroll 1
  for (int t = 0; t < 8; ++t) {
    const int cur = t & 1;
    const int s0 = kbase + t * 64;
    // issue next tile's K/Ks global loads first (latency hides under consume)
    if (t < 7) {
      const int s0n = s0 + 64;
      rk = *(const short8b*)&Kb [(size_t)(s0n + gK) * 32 + kseg * 8];
      rs = *(const short8b*)&Ksb[(size_t)(s0n + gK) * 32 + kseg * 8];
    }
    // V direct from L2-resident Vt (consumed after softmax, ~400cy later)
    short8b bV[2][2];
#pragma unroll
    for (int kk = 0; kk < 2; ++kk)
#pragma unroll
      for (int dh = 0; dh < 2; ++dh)
        bV[kk][dh] = *(const short8b*)&Vb[(dh * 16 + ln) * 2048 + s0 + kk * 32 + kg * 8];
    // key identities for this tile
    const int* ip = kid_g + s0 + kg * 8;
    int4 t0 = *(const int4*)(ip);
    int4 t1 = *(const int4*)(ip + 32);
    int4 t2 = *(const int4*)(ip + 4);
    int4 t3 = *(const int4*)(ip + 36);
    int sd[4][4] = {{t0.x, t0.y, t0.z, t0.w}, {t1.x, t1.y, t1.z, t1.w},
                    {t2.x, t2.y, t2.z, t2.w}, {t3.x, t3.y, t3.z, t3.w}};

    // consume buf[cur]
    short8b aK[4], aS[4];
#pragma unroll
    for (int sub = 0; sub < 4; ++sub) {
      aK[sub] = *(const short8b*)&Klds [cur][sub * 16 + ln][kg * 8];
      aS[sub] = *(const short8b*)&Kslds[cur][sub * 16 + ln][kg * 8];
    }

    float4v ci[4], cs[4];
    float4v z = {0.f, 0.f, 0.f, 0.f};
    __builtin_amdgcn_s_setprio(1);
#pragma unroll
    for (int sub = 0; sub < 4; ++sub) {
      ci[sub] = __builtin_amdgcn_mfma_f32_16x16x32_bf16(aK[sub], bQ,  z, 0, 0, 0);
      cs[sub] = __builtin_amdgcn_mfma_f32_16x16x32_bf16(aS[sub], bQf, z, 0, 0, 0);
    }
    __builtin_amdgcn_s_setprio(0);
    // blend by agent identity + exp2 (fixed base, all independent)
    float p[4][4];
#pragma unroll
    for (int sub = 0; sub < 4; ++sub)
#pragma unroll
      for (int r = 0; r < 4; ++r)
        p[sub][r] = exp2f((sd[sub][r] == qidq) ? cs[sub][r] : ci[sub][r]);
    float y0 = (p[0][0] + p[0][1]) + (p[0][2] + p[0][3]);
    float y1 = (p[1][0] + p[1][1]) + (p[1][2] + p[1][3]);
    float y2 = (p[2][0] + p[2][1]) + (p[2][2] + p[2][3]);
    float y3 = (p[3][0] + p[3][1]) + (p[3][2] + p[3][3]);
    lacc += (y0 + y1) + (y2 + y3);
    // P -> PV A-fragments, fully in-lane (permutation applied at stage time)
    union { short8b v; unsigned short us[8]; } apk[2];
#pragma unroll
    for (int kk = 0; kk < 2; ++kk) {
      apk[kk].us[0] = f2bf_bits(p[kk][0]);     apk[kk].us[1] = f2bf_bits(p[kk][1]);
      apk[kk].us[2] = f2bf_bits(p[kk][2]);     apk[kk].us[3] = f2bf_bits(p[kk][3]);
      apk[kk].us[4] = f2bf_bits(p[kk + 2][0]); apk[kk].us[5] = f2bf_bits(p[kk + 2][1]);
      apk[kk].us[6] = f2bf_bits(p[kk + 2][2]); apk[kk].us[7] = f2bf_bits(p[kk + 2][3]);
    }
    __builtin_amdgcn_s_setprio(1);
#pragma unroll
    for (int kk = 0; kk < 2; ++kk) {
      O0 = __builtin_amdgcn_mfma_f32_16x16x32_bf16(apk[kk].v, bV[kk][0], O0, 0, 0, 0);
      O1 = __builtin_amdgcn_mfma_f32_16x16x32_bf16(apk[kk].v, bV[kk][1], O1, 0, 0, 0);
    }
    __builtin_amdgcn_s_setprio(0);

    // write next tile into the other buffer (safe: others read buf[cur] only)
    if (t < 7) {
      *(short8b*)&Klds [cur ^ 1][krho][kseg * 8] = rk;
      *(short8b*)&Kslds[cur ^ 1][krho][kseg * 8] = rs;
    }
    __syncthreads();
  }

  // epilogue: per-lane l partial reduced across kg groups; write partials
  float ps = lacc;
  ps += __shfl_xor(ps, 16);
  ps += __shfl_xor(ps, 32);          // all lanes: l_partial for q = q0 + ln
  float* pob = PO + (size_t)(split * 16 + bh) * 2048 * 32;
  float* plb = PL + (size_t)(split * 16 + bh) * 2048;
#pragma unroll
  for (int r = 0; r < 4; ++r) {
    int q = q0 + kg * 4 + r;
    pob[(size_t)q * 32 + ln]      = O0[r];
    pob[(size_t)q * 32 + 16 + ln] = O1[r];
  }
  if (kg == 0) plb[q0 + ln] = ps;
}

// ---------------------------------------------------------------------------
// K2b: merge splitS=4 partials -> Ab (4096 x 256 bf16). m=0 -> plain sums.
// Coalesced: 8 threads per q (wave reads 1 KB contiguous per split).
// ---------------------------------------------------------------------------
__global__ __launch_bounds__(256) void combine_splits(
    const float* __restrict__ PO, const float* __restrict__ PL,
    __hip_bfloat16* __restrict__ Ab) {
  const int blk = blockIdx.x;                 // 1024 blocks: 64 per bh
  const int bh = blk >> 6;
  const int q = ((blk & 63) << 5) | (threadIdx.x >> 3);   // 32 q per block
  const int d4 = threadIdx.x & 7;             // float4 index within 32 d
  const int n = bh >> 3, h = bh & 7;
  float L = 0.f;
#pragma unroll
  for (int s = 0; s < 4; ++s) L += PL[(size_t)(s * 16 + bh) * 2048 + q];
  float inv = 1.f / L;
  float4 acc = {0.f, 0.f, 0.f, 0.f};
#pragma unroll
  for (int s = 0; s < 4; ++s) {
    float4 v = *(const float4*)&PO[((size_t)(s * 16 + bh) * 2048 + q) * 32 + d4 * 4];
    acc.x += v.x; acc.y += v.y; acc.z += v.z; acc.w += v.w;
  }
  union { ushort4 u; __hip_bfloat16 hh[4]; } o;
  o.hh[0] = __float2bfloat16(acc.x * inv); o.hh[1] = __float2bfloat16(acc.y * inv);
  o.hh[2] = __float2bfloat16(acc.z * inv); o.hh[3] = __float2bfloat16(acc.w * inv);
  *(ushort4*)&Ab[((size_t)q * 2 + n) * 256 + h * 32 + d4 * 4] = o.u;
}

// ---------------------------------------------------------------------------
// K3: out projection, 64x64 tiles. W_o converted f32->bf16 inline in staging.
// out(4096 x 256, f32) = Ab @ W_o^T + bias
// ---------------------------------------------------------------------------
__global__ __launch_bounds__(256) void out_gemm(
    const __hip_bfloat16* __restrict__ A, const float* __restrict__ Wo,
    const float* __restrict__ bias, float* __restrict__ out) {
    __shared__ __hip_bfloat16 At[64][40];
    __shared__ __hip_bfloat16 Bt[64][40];
    const int tid = threadIdx.x;
    const int lane = tid & 63, w = tid >> 6;
    const int ln = lane & 15, kg = lane >> 4;
    const int wr = w >> 1, wc = w & 1;
    const int rowBase = blockIdx.y * 64;
    const int colBase = blockIdx.x * 64;
    float4v acc[2][2] = {};

    for (int kt = 0; kt < 8; ++kt) {
        int row = tid >> 2, c = tid & 3;
        *(short8b*)&At[row][c * 8] =
            *(const short8b*)&A[(size_t)(rowBase + row) * 256 + kt * 32 + c * 8];
        float fb[8];
        *(float4*)&fb[0] = *(const float4*)&Wo[(size_t)(colBase + row) * 256 + kt * 32 + c * 8];
        *(float4*)&fb[4] = *(const float4*)&Wo[(size_t)(colBase + row) * 256 + kt * 32 + c * 8 + 4];
        *(short8b*)&Bt[row][c * 8] = cvt8(fb);
        __syncthreads();
        short8b a[2], b[2];
#pragma unroll
        for (int mi = 0; mi < 2; ++mi) a[mi] = *(const short8b*)&At[wr * 32 + mi * 16 + ln][kg * 8];
#pragma unroll
        for (int nj = 0; nj < 2; ++nj) b[nj] = *(const short8b*)&Bt[wc * 32 + nj * 16 + ln][kg * 8];
#pragma unroll
        for (int mi = 0; mi < 2; ++mi)
#pragma unroll
            for (int nj = 0; nj < 2; ++nj)
                acc[mi][nj] = __builtin_amdgcn_mfma_f32_16x16x32_bf16(a[mi], b[nj], acc[mi][nj], 0, 0, 0);
        __syncthreads();
    }

#pragma unroll
    for (int mi = 0; mi < 2; ++mi) {
#pragma unroll
        for (int nj = 0; nj < 2; ++nj) {
            int j = colBase + wc * 32 + nj * 16 + ln;
            float bj = bias[j];
#pragma unroll
            for (int r = 0; r < 4; ++r) {
                int row = rowBase + wr * 32 + mi * 16 + kg * 4 + r;
                out[row * 256 + j] = acc[mi][nj][r] + bj;
            }
        }
    }
}

// ---------------------------------------------------------------------------
extern "C" void kernel_launch(void* const* d_in, const int* in_sizes, int n_in,
                              void* d_out, int out_size, void* d_ws, size_t ws_size,
                              hipStream_t stream) {
    const float* query = (const float*)d_in[0];
    const float* W_in  = (const float*)d_in[1];
    const float* b_in  = (const float*)d_in[2];
    const float* W_s   = (const float*)d_in[3];
    const float* b_s   = (const float*)d_in[4];
    const float* W_o   = (const float*)d_in[5];
    const float* b_o   = (const float*)d_in[6];
    const int*   qids  = (const int*)d_in[7];
    const int*   kids  = (const int*)d_in[8];
    float* out = (float*)d_out;

    __hip_bfloat16* Qs  = (__hip_bfloat16*)d_ws;       // [16][2048][32]
    __hip_bfloat16* Kg  = Qs + 16 * 2048 * 32;
    __hip_bfloat16* Vt  = Kg + 16 * 2048 * 32;         // [16][32][2048]
    __hip_bfloat16* Qf  = Vt + 16 * 2048 * 32;
    __hip_bfloat16* Kf  = Qf + 16 * 2048 * 32;
    __hip_bfloat16* Ab  = Kf + 16 * 2048 * 32;         // 4096 x 256
    __hip_bfloat16* Xb  = Ab + 4096 * 256;             // 4096 x 256
    float* PO = (float*)(Xb + 4096 * 256);             // [4][16][2048][32] f32
    float* PL = PO + (size_t)4 * 16 * 2048 * 32;       // [4][16][2048] f32

    cast_X<<<1024, 256, 0, stream>>>(query, Xb);
    proj_gemm<<<dim3(20, 32), 256, 0, stream>>>(Xb, W_in, W_s, b_in, b_s,
                                                Qs, Kg, Vt, Qf, Kf);
    agent_attn<<<2048, 256, 0, stream>>>(Qs, Kg, Vt, Qf, Kf, qids, kids, PO, PL);
    combine_splits<<<1024, 256, 0, stream>>>(PO, PL, Ab);
    out_gemm<<<dim3(4, 64), 256, 0, stream>>>(Ab, W_o, b_o, out);
}

// Round 13
// 82.808 us; speedup vs baseline: 2.8518x; 2.8518x over previous
//
#include <hip/hip_runtime.h>
#include <hip/hip_bf16.h>

typedef __attribute__((ext_vector_type(8))) short short8b;
typedef __attribute__((ext_vector_type(4))) float float4v;

static __device__ __forceinline__ unsigned short f2bf_bits(float f) {
  union { __hip_bfloat16 h; unsigned short u; } c;
  c.h = __float2bfloat16(f);
  return c.u;
}

static __device__ __forceinline__ short8b cvt8(const float* s) {
  union { short8b v; unsigned short us[8]; } o;
#pragma unroll
  for (int i = 0; i < 8; ++i) o.us[i] = f2bf_bits(s[i]);
  return o.v;
}

// ---------------------------------------------------------------------------
// K0: X f32 -> bf16 (proj_gemm re-reads X 20x, so pre-cast pays)
// ---------------------------------------------------------------------------
__global__ __launch_bounds__(256) void cast_X(const float* __restrict__ src,
                                              __hip_bfloat16* __restrict__ dst) {
  int i = blockIdx.x * 256 + threadIdx.x;      // 262144 float4 groups
  float4 v = reinterpret_cast<const float4*>(src)[i];
  union { ushort4 u; __hip_bfloat16 h[4]; } o;
  o.h[0] = __float2bfloat16(v.x); o.h[1] = __float2bfloat16(v.y);
  o.h[2] = __float2bfloat16(v.z); o.h[3] = __float2bfloat16(v.w);
  reinterpret_cast<ushort4*>(dst)[i] = o.u;
}

// ---------------------------------------------------------------------------
// K1: projection GEMM (R9 version). C(4096 x 1280) = Xb @ W^T, 128x64 tiles.
// W f32 converted in staging. Q-scaling includes log2(e). Epilogue scatters
// per-head: Qs,K,Qf,Kf : [bh][2048][32]    V -> Vt : [bh][32][2048]
// ---------------------------------------------------------------------------
__global__ __launch_bounds__(256) void proj_gemm(
    const __hip_bfloat16* __restrict__ Xb, const float* __restrict__ W1,
    const float* __restrict__ W2,
    const float* __restrict__ bias, const float* __restrict__ bias_s,
    __hip_bfloat16* __restrict__ Qs, __hip_bfloat16* __restrict__ Kg,
    __hip_bfloat16* __restrict__ Vt, __hip_bfloat16* __restrict__ Qf,
    __hip_bfloat16* __restrict__ Kf) {
    __shared__ __hip_bfloat16 At[128][40];
    __shared__ __hip_bfloat16 Bt[64][40];
    const int tid = threadIdx.x;
    const int lane = tid & 63, w = tid >> 6;
    const int ln = lane & 15, kg = lane >> 4;
    const int wr = w >> 1, wc = w & 1;
    const int rowBase = blockIdx.y * 128;
    const int colBase = blockIdx.x * 64;
    const float* Wsrc = (colBase < 768) ? (W1 + (size_t)colBase * 256)
                                        : (W2 + (size_t)(colBase - 768) * 256);
    float4v acc[4][2] = {};

    for (int kt = 0; kt < 8; ++kt) {
        int cid = tid;
#pragma unroll
        for (int p = 0; p < 2; ++p, cid += 256) {
            int row = cid >> 2, c = cid & 3;
            *(short8b*)&At[row][c * 8] =
                *(const short8b*)&Xb[(size_t)(rowBase + row) * 256 + kt * 32 + c * 8];
        }
        {
            int row = tid >> 2, c = tid & 3;
            float fb[8];
            *(float4*)&fb[0] = *(const float4*)&Wsrc[(size_t)row * 256 + kt * 32 + c * 8];
            *(float4*)&fb[4] = *(const float4*)&Wsrc[(size_t)row * 256 + kt * 32 + c * 8 + 4];
            *(short8b*)&Bt[row][c * 8] = cvt8(fb);
        }
        __syncthreads();
        short8b a[4], b[2];
#pragma unroll
        for (int mi = 0; mi < 4; ++mi) a[mi] = *(const short8b*)&At[wr * 64 + mi * 16 + ln][kg * 8];
#pragma unroll
        for (int nj = 0; nj < 2; ++nj) b[nj] = *(const short8b*)&Bt[wc * 32 + nj * 16 + ln][kg * 8];
#pragma unroll
        for (int mi = 0; mi < 4; ++mi)
#pragma unroll
            for (int nj = 0; nj < 2; ++nj)
                acc[mi][nj] = __builtin_amdgcn_mfma_f32_16x16x32_bf16(a[mi], b[nj], acc[mi][nj], 0, 0, 0);
        __syncthreads();
    }

    const float scaling = 0.17677669529663687f * 1.4426950408889634f;  // 32^-0.5 * log2(e)
#pragma unroll
    for (int mi = 0; mi < 4; ++mi) {
#pragma unroll
        for (int nj = 0; nj < 2; ++nj) {
            int j = colBase + wc * 32 + nj * 16 + ln;
            float bj = (j < 768) ? bias[j] : bias_s[j - 768];
#pragma unroll
            for (int r = 0; r < 4; ++r) {
                int row = rowBase + wr * 64 + mi * 16 + kg * 4 + r;
                float val = acc[mi][nj][r] + bj;
                int l = row >> 1, n = row & 1;
                if (j < 256) {
                    int h = j >> 5, d = j & 31;
                    Qs[(((n << 3) + h) * 2048 + l) * 32 + d] = __float2bfloat16(val * scaling);
                } else if (j < 512) {
                    int e = j - 256, h = e >> 5, d = e & 31;
                    Kg[(((n << 3) + h) * 2048 + l) * 32 + d] = __float2bfloat16(val);
                } else if (j < 768) {
                    int e = j - 512, h = e >> 5, d = e & 31;
                    Vt[(((n << 3) + h) * 32 + d) * 2048 + l] = __float2bfloat16(val);
                } else if (j < 1024) {
                    int e = j - 768, h = e >> 5, d = e & 31;
                    Qf[(((n << 3) + h) * 2048 + l) * 32 + d] = __float2bfloat16(val * scaling);
                } else {
                    int e = j - 1024, h = e >> 5, d = e & 31;
                    Kf[(((n << 3) + h) * 2048 + l) * 32 + d] = __float2bfloat16(val);
                }
            }
        }
    }
}

// ---------------------------------------------------------------------------
// K2: agent-aware flash attention, LDS-staged K/Ks + pipelined, splitS=4.
// grid 2048 = 8 xcd x {2 bh, 32 qg, 4 split}; block 256 thr = 4 waves x 16 q.
// V NOT staged (L2-resident per-head Vt, read direct) -> LDS 18.4 KB.
// launch_bounds(256,2) -- R12's (256,6) forced VGPR=40 and massive scratch
// spill (337MB fetch); let the allocator float like R9 (VGPR 60, no spill).
// Per tile: K/Ks in LDS [64][36] with PV permutation applied at stage time,
// double-buffered, one barrier/tile, register prefetch of next K/Ks.
// Swapped QK^T, fixed softmax base m=0 (exp2 domain), in-lane P->A-frag, PV.
// Partial (O,l) -> PO/PL (f32).
// ---------------------------------------------------------------------------
__global__ __launch_bounds__(256, 2) void agent_attn(
    const __hip_bfloat16* __restrict__ Qs, const __hip_bfloat16* __restrict__ Kg,
    const __hip_bfloat16* __restrict__ Vt, const __hip_bfloat16* __restrict__ Qf,
    const __hip_bfloat16* __restrict__ Kf, const int* __restrict__ qid_g,
    const int* __restrict__ kid_g, float* __restrict__ PO, float* __restrict__ PL) {
  __shared__ __hip_bfloat16 Klds[2][64][36];
  __shared__ __hip_bfloat16 Kslds[2][64][36];

  const int tid = threadIdx.x;
  const int lane = tid & 63, w = tid >> 6;
  const int ln = lane & 15, kg = lane >> 4;

  const int flat = blockIdx.x;               // 2048 = 8 xcd * (2 bh | 32 qg | 4 split)
  const int slot = flat >> 3;
  const int bh = ((flat & 7) << 1) | (slot & 1);
  const int rest = slot >> 1;                // 0..127
  const int qg = rest & 31, split = rest >> 5;
  const int q0 = qg * 64 + w * 16;
  const int kbase = split * 512;

  const __hip_bfloat16* Qb  = Qs + (size_t)bh * 2048 * 32;
  const __hip_bfloat16* Qfb = Qf + (size_t)bh * 2048 * 32;
  const __hip_bfloat16* Kb  = Kg + (size_t)bh * 2048 * 32;
  const __hip_bfloat16* Ksb = Kf + (size_t)bh * 2048 * 32;
  const __hip_bfloat16* Vb  = Vt + (size_t)bh * 32 * 2048;

  // staging geometry (constant per thread)
  const int krho = tid >> 2, kseg = tid & 3;       // K/Ks: row [0,64), 4x8 bf16 segs
  const int ksub = krho >> 4, ki = krho & 15;
  // permuted global key for LDS row krho: g = (i>>2)*8 + (i&3) + off[sub]
  const int gK = ((ki >> 2) << 3) + (ki & 3) + ((ksub & 1) << 5) + ((ksub >> 1) << 2);

  // Q fragments (B-operand: row=q=ln, k=kg*8+j) + per-lane q identity
  short8b bQ  = *(const short8b*)&Qb [(q0 + ln) * 32 + kg * 8];
  short8b bQf = *(const short8b*)&Qfb[(q0 + ln) * 32 + kg * 8];
  const int qidq = qid_g[q0 + ln];

  float lacc = 0.f;                // per-lane partial softmax denominator
  float4v O0 = {0.f, 0.f, 0.f, 0.f}, O1 = {0.f, 0.f, 0.f, 0.f};

  // prologue: stage tile 0 into buffer 0
  {
    short8b rk = *(const short8b*)&Kb [(size_t)(kbase + gK) * 32 + kseg * 8];
    short8b rs = *(const short8b*)&Ksb[(size_t)(kbase + gK) * 32 + kseg * 8];
    *(short8b*)&Klds [0][krho][kseg * 8] = rk;
    *(short8b*)&Kslds[0][krho][kseg * 8] = rs;
  }
  __syncthreads();

  short8b rk, rs;
#pragma unroll 1
  for (int t = 0; t < 8; ++t) {
    const int cur = t & 1;
    const int s0 = kbase + t * 64;
    // issue next tile's K/Ks global loads first (latency hides under consume)
    if (t < 7) {
      const int s0n = s0 + 64;
      rk = *(const short8b*)&Kb [(size_t)(s0n + gK) * 32 + kseg * 8];
      rs = *(const short8b*)&Ksb[(size_t)(s0n + gK) * 32 + kseg * 8];
    }
    // V direct from L2-resident Vt (consumed after softmax, ~400cy later)
    short8b bV[2][2];
#pragma unroll
    for (int kk = 0; kk < 2; ++kk)
#pragma unroll
      for (int dh = 0; dh < 2; ++dh)
        bV[kk][dh] = *(const short8b*)&Vb[(dh * 16 + ln) * 2048 + s0 + kk * 32 + kg * 8];
    // key identities for this tile
    const int* ip = kid_g + s0 + kg * 8;
    int4 t0 = *(const int4*)(ip);
    int4 t1 = *(const int4*)(ip + 32);
    int4 t2 = *(const int4*)(ip + 4);
    int4 t3 = *(const int4*)(ip + 36);
    int sd[4][4] = {{t0.x, t0.y, t0.z, t0.w}, {t1.x, t1.y, t1.z, t1.w},
                    {t2.x, t2.y, t2.z, t2.w}, {t3.x, t3.y, t3.z, t3.w}};

    // consume buf[cur]
    short8b aK[4], aS[4];
#pragma unroll
    for (int sub = 0; sub < 4; ++sub) {
      aK[sub] = *(const short8b*)&Klds [cur][sub * 16 + ln][kg * 8];
      aS[sub] = *(const short8b*)&Kslds[cur][sub * 16 + ln][kg * 8];
    }

    float4v ci[4], cs[4];
    float4v z = {0.f, 0.f, 0.f, 0.f};
    __builtin_amdgcn_s_setprio(1);
#pragma unroll
    for (int sub = 0; sub < 4; ++sub) {
      ci[sub] = __builtin_amdgcn_mfma_f32_16x16x32_bf16(aK[sub], bQ,  z, 0, 0, 0);
      cs[sub] = __builtin_amdgcn_mfma_f32_16x16x32_bf16(aS[sub], bQf, z, 0, 0, 0);
    }
    __builtin_amdgcn_s_setprio(0);
    // blend by agent identity + exp2 (fixed base, all independent)
    float p[4][4];
#pragma unroll
    for (int sub = 0; sub < 4; ++sub)
#pragma unroll
      for (int r = 0; r < 4; ++r)
        p[sub][r] = exp2f((sd[sub][r] == qidq) ? cs[sub][r] : ci[sub][r]);
    float y0 = (p[0][0] + p[0][1]) + (p[0][2] + p[0][3]);
    float y1 = (p[1][0] + p[1][1]) + (p[1][2] + p[1][3]);
    float y2 = (p[2][0] + p[2][1]) + (p[2][2] + p[2][3]);
    float y3 = (p[3][0] + p[3][1]) + (p[3][2] + p[3][3]);
    lacc += (y0 + y1) + (y2 + y3);
    // P -> PV A-fragments, fully in-lane (permutation applied at stage time)
    union { short8b v; unsigned short us[8]; } apk[2];
#pragma unroll
    for (int kk = 0; kk < 2; ++kk) {
      apk[kk].us[0] = f2bf_bits(p[kk][0]);     apk[kk].us[1] = f2bf_bits(p[kk][1]);
      apk[kk].us[2] = f2bf_bits(p[kk][2]);     apk[kk].us[3] = f2bf_bits(p[kk][3]);
      apk[kk].us[4] = f2bf_bits(p[kk + 2][0]); apk[kk].us[5] = f2bf_bits(p[kk + 2][1]);
      apk[kk].us[6] = f2bf_bits(p[kk + 2][2]); apk[kk].us[7] = f2bf_bits(p[kk + 2][3]);
    }
    __builtin_amdgcn_s_setprio(1);
#pragma unroll
    for (int kk = 0; kk < 2; ++kk) {
      O0 = __builtin_amdgcn_mfma_f32_16x16x32_bf16(apk[kk].v, bV[kk][0], O0, 0, 0, 0);
      O1 = __builtin_amdgcn_mfma_f32_16x16x32_bf16(apk[kk].v, bV[kk][1], O1, 0, 0, 0);
    }
    __builtin_amdgcn_s_setprio(0);

    // write next tile into the other buffer (safe: others read buf[cur] only)
    if (t < 7) {
      *(short8b*)&Klds [cur ^ 1][krho][kseg * 8] = rk;
      *(short8b*)&Kslds[cur ^ 1][krho][kseg * 8] = rs;
    }
    __syncthreads();
  }

  // epilogue: per-lane l partial reduced across kg groups; write partials
  float ps = lacc;
  ps += __shfl_xor(ps, 16);
  ps += __shfl_xor(ps, 32);          // all lanes: l_partial for q = q0 + ln
  float* pob = PO + (size_t)(split * 16 + bh) * 2048 * 32;
  float* plb = PL + (size_t)(split * 16 + bh) * 2048;
#pragma unroll
  for (int r = 0; r < 4; ++r) {
    int q = q0 + kg * 4 + r;
    pob[(size_t)q * 32 + ln]      = O0[r];
    pob[(size_t)q * 32 + 16 + ln] = O1[r];
  }
  if (kg == 0) plb[q0 + ln] = ps;
}

// ---------------------------------------------------------------------------
// K2b: merge splitS=4 partials -> Ab (4096 x 256 bf16). m=0 -> plain sums.
// Coalesced: 8 threads per q (wave reads 1 KB contiguous per split).
// ---------------------------------------------------------------------------
__global__ __launch_bounds__(256) void combine_splits(
    const float* __restrict__ PO, const float* __restrict__ PL,
    __hip_bfloat16* __restrict__ Ab) {
  const int blk = blockIdx.x;                 // 1024 blocks: 64 per bh
  const int bh = blk >> 6;
  const int q = ((blk & 63) << 5) | (threadIdx.x >> 3);   // 32 q per block
  const int d4 = threadIdx.x & 7;             // float4 index within 32 d
  const int n = bh >> 3, h = bh & 7;
  float L = 0.f;
#pragma unroll
  for (int s = 0; s < 4; ++s) L += PL[(size_t)(s * 16 + bh) * 2048 + q];
  float inv = 1.f / L;
  float4 acc = {0.f, 0.f, 0.f, 0.f};
#pragma unroll
  for (int s = 0; s < 4; ++s) {
    float4 v = *(const float4*)&PO[((size_t)(s * 16 + bh) * 2048 + q) * 32 + d4 * 4];
    acc.x += v.x; acc.y += v.y; acc.z += v.z; acc.w += v.w;
  }
  union { ushort4 u; __hip_bfloat16 hh[4]; } o;
  o.hh[0] = __float2bfloat16(acc.x * inv); o.hh[1] = __float2bfloat16(acc.y * inv);
  o.hh[2] = __float2bfloat16(acc.z * inv); o.hh[3] = __float2bfloat16(acc.w * inv);
  *(ushort4*)&Ab[((size_t)q * 2 + n) * 256 + h * 32 + d4 * 4] = o.u;
}

// ---------------------------------------------------------------------------
// K3: out projection, 64x64 tiles. W_o converted f32->bf16 inline in staging.
// out(4096 x 256, f32) = Ab @ W_o^T + bias
// ---------------------------------------------------------------------------
__global__ __launch_bounds__(256) void out_gemm(
    const __hip_bfloat16* __restrict__ A, const float* __restrict__ Wo,
    const float* __restrict__ bias, float* __restrict__ out) {
    __shared__ __hip_bfloat16 At[64][40];
    __shared__ __hip_bfloat16 Bt[64][40];
    const int tid = threadIdx.x;
    const int lane = tid & 63, w = tid >> 6;
    const int ln = lane & 15, kg = lane >> 4;
    const int wr = w >> 1, wc = w & 1;
    const int rowBase = blockIdx.y * 64;
    const int colBase = blockIdx.x * 64;
    float4v acc[2][2] = {};

    for (int kt = 0; kt < 8; ++kt) {
        int row = tid >> 2, c = tid & 3;
        *(short8b*)&At[row][c * 8] =
            *(const short8b*)&A[(size_t)(rowBase + row) * 256 + kt * 32 + c * 8];
        float fb[8];
        *(float4*)&fb[0] = *(const float4*)&Wo[(size_t)(colBase + row) * 256 + kt * 32 + c * 8];
        *(float4*)&fb[4] = *(const float4*)&Wo[(size_t)(colBase + row) * 256 + kt * 32 + c * 8 + 4];
        *(short8b*)&Bt[row][c * 8] = cvt8(fb);
        __syncthreads();
        short8b a[2], b[2];
#pragma unroll
        for (int mi = 0; mi < 2; ++mi) a[mi] = *(const short8b*)&At[wr * 32 + mi * 16 + ln][kg * 8];
#pragma unroll
        for (int nj = 0; nj < 2; ++nj) b[nj] = *(const short8b*)&Bt[wc * 32 + nj * 16 + ln][kg * 8];
#pragma unroll
        for (int mi = 0; mi < 2; ++mi)
#pragma unroll
            for (int nj = 0; nj < 2; ++nj)
                acc[mi][nj] = __builtin_amdgcn_mfma_f32_16x16x32_bf16(a[mi], b[nj], acc[mi][nj], 0, 0, 0);
        __syncthreads();
    }

#pragma unroll
    for (int mi = 0; mi < 2; ++mi) {
#pragma unroll
        for (int nj = 0; nj < 2; ++nj) {
            int j = colBase + wc * 32 + nj * 16 + ln;
            float bj = bias[j];
#pragma unroll
            for (int r = 0; r < 4; ++r) {
                int row = rowBase + wr * 32 + mi * 16 + kg * 4 + r;
                out[row * 256 + j] = acc[mi][nj][r] + bj;
            }
        }
    }
}

// ---------------------------------------------------------------------------
extern "C" void kernel_launch(void* const* d_in, const int* in_sizes, int n_in,
                              void* d_out, int out_size, void* d_ws, size_t ws_size,
                              hipStream_t stream) {
    const float* query = (const float*)d_in[0];
    const float* W_in  = (const float*)d_in[1];
    const float* b_in  = (const float*)d_in[2];
    const float* W_s   = (const float*)d_in[3];
    const float* b_s   = (const float*)d_in[4];
    const float* W_o   = (const float*)d_in[5];
    const float* b_o   = (const float*)d_in[6];
    const int*   qids  = (const int*)d_in[7];
    const int*   kids  = (const int*)d_in[8];
    float* out = (float*)d_out;

    __hip_bfloat16* Qs  = (__hip_bfloat16*)d_ws;       // [16][2048][32]
    __hip_bfloat16* Kg  = Qs + 16 * 2048 * 32;
    __hip_bfloat16* Vt  = Kg + 16 * 2048 * 32;         // [16][32][2048]
    __hip_bfloat16* Qf  = Vt + 16 * 2048 * 32;
    __hip_bfloat16* Kf  = Qf + 16 * 2048 * 32;
    __hip_bfloat16* Ab  = Kf + 16 * 2048 * 32;         // 4096 x 256
    __hip_bfloat16* Xb  = Ab + 4096 * 256;             // 4096 x 256
    float* PO = (float*)(Xb + 4096 * 256);             // [4][16][2048][32] f32
    float* PL = PO + (size_t)4 * 16 * 2048 * 32;       // [4][16][2048] f32

    cast_X<<<1024, 256, 0, stream>>>(query, Xb);
    proj_gemm<<<dim3(20, 32), 256, 0, stream>>>(Xb, W_in, W_s, b_in, b_s,
                                                Qs, Kg, Vt, Qf, Kf);
    agent_attn<<<2048, 256, 0, stream>>>(Qs, Kg, Vt, Qf, Kf, qids, kids, PO, PL);
    combine_splits<<<1024, 256, 0, stream>>>(PO, PL, Ab);
    out_gemm<<<dim3(4, 64), 256, 0, stream>>>(Ab, W_o, b_o, out);
}

// Round 14
// 66.897 us; speedup vs baseline: 3.5301x; 1.2378x over previous
//
#include <hip/hip_runtime.h>
#include <hip/hip_bf16.h>

typedef __attribute__((ext_vector_type(8))) short short8b;
typedef __attribute__((ext_vector_type(4))) float float4v;

static __device__ __forceinline__ unsigned short f2bf_bits(float f) {
  union { __hip_bfloat16 h; unsigned short u; } c;
  c.h = __float2bfloat16(f);
  return c.u;
}

static __device__ __forceinline__ short8b cvt8(const float* s) {
  union { short8b v; unsigned short us[8]; } o;
#pragma unroll
  for (int i = 0; i < 8; ++i) o.us[i] = f2bf_bits(s[i]);
  return o.v;
}

// ---------------------------------------------------------------------------
// K0: X f32 -> bf16 (proj_gemm re-reads X 20x, so pre-cast pays)
// ---------------------------------------------------------------------------
__global__ __launch_bounds__(256) void cast_X(const float* __restrict__ src,
                                              __hip_bfloat16* __restrict__ dst) {
  int i = blockIdx.x * 256 + threadIdx.x;      // 262144 float4 groups
  float4 v = reinterpret_cast<const float4*>(src)[i];
  union { ushort4 u; __hip_bfloat16 h[4]; } o;
  o.h[0] = __float2bfloat16(v.x); o.h[1] = __float2bfloat16(v.y);
  o.h[2] = __float2bfloat16(v.z); o.h[3] = __float2bfloat16(v.w);
  reinterpret_cast<ushort4*>(dst)[i] = o.u;
}

// ---------------------------------------------------------------------------
// K1: projection GEMM (R9 version). C(4096 x 1280) = Xb @ W^T, 128x64 tiles.
// W f32 converted in staging. Q-scaling includes log2(e). Epilogue scatters
// per-head: Qs,K,Qf,Kf : [bh][2048][32]    V -> Vt : [bh][32][2048]
// ---------------------------------------------------------------------------
__global__ __launch_bounds__(256) void proj_gemm(
    const __hip_bfloat16* __restrict__ Xb, const float* __restrict__ W1,
    const float* __restrict__ W2,
    const float* __restrict__ bias, const float* __restrict__ bias_s,
    __hip_bfloat16* __restrict__ Qs, __hip_bfloat16* __restrict__ Kg,
    __hip_bfloat16* __restrict__ Vt, __hip_bfloat16* __restrict__ Qf,
    __hip_bfloat16* __restrict__ Kf) {
    __shared__ __hip_bfloat16 At[128][40];
    __shared__ __hip_bfloat16 Bt[64][40];
    const int tid = threadIdx.x;
    const int lane = tid & 63, w = tid >> 6;
    const int ln = lane & 15, kg = lane >> 4;
    const int wr = w >> 1, wc = w & 1;
    const int rowBase = blockIdx.y * 128;
    const int colBase = blockIdx.x * 64;
    const float* Wsrc = (colBase < 768) ? (W1 + (size_t)colBase * 256)
                                        : (W2 + (size_t)(colBase - 768) * 256);
    float4v acc[4][2] = {};

    for (int kt = 0; kt < 8; ++kt) {
        int cid = tid;
#pragma unroll
        for (int p = 0; p < 2; ++p, cid += 256) {
            int row = cid >> 2, c = cid & 3;
            *(short8b*)&At[row][c * 8] =
                *(const short8b*)&Xb[(size_t)(rowBase + row) * 256 + kt * 32 + c * 8];
        }
        {
            int row = tid >> 2, c = tid & 3;
            float fb[8];
            *(float4*)&fb[0] = *(const float4*)&Wsrc[(size_t)row * 256 + kt * 32 + c * 8];
            *(float4*)&fb[4] = *(const float4*)&Wsrc[(size_t)row * 256 + kt * 32 + c * 8 + 4];
            *(short8b*)&Bt[row][c * 8] = cvt8(fb);
        }
        __syncthreads();
        short8b a[4], b[2];
#pragma unroll
        for (int mi = 0; mi < 4; ++mi) a[mi] = *(const short8b*)&At[wr * 64 + mi * 16 + ln][kg * 8];
#pragma unroll
        for (int nj = 0; nj < 2; ++nj) b[nj] = *(const short8b*)&Bt[wc * 32 + nj * 16 + ln][kg * 8];
#pragma unroll
        for (int mi = 0; mi < 4; ++mi)
#pragma unroll
            for (int nj = 0; nj < 2; ++nj)
                acc[mi][nj] = __builtin_amdgcn_mfma_f32_16x16x32_bf16(a[mi], b[nj], acc[mi][nj], 0, 0, 0);
        __syncthreads();
    }

    const float scaling = 0.17677669529663687f * 1.4426950408889634f;  // 32^-0.5 * log2(e)
#pragma unroll
    for (int mi = 0; mi < 4; ++mi) {
#pragma unroll
        for (int nj = 0; nj < 2; ++nj) {
            int j = colBase + wc * 32 + nj * 16 + ln;
            float bj = (j < 768) ? bias[j] : bias_s[j - 768];
#pragma unroll
            for (int r = 0; r < 4; ++r) {
                int row = rowBase + wr * 64 + mi * 16 + kg * 4 + r;
                float val = acc[mi][nj][r] + bj;
                int l = row >> 1, n = row & 1;
                if (j < 256) {
                    int h = j >> 5, d = j & 31;
                    Qs[(((n << 3) + h) * 2048 + l) * 32 + d] = __float2bfloat16(val * scaling);
                } else if (j < 512) {
                    int e = j - 256, h = e >> 5, d = e & 31;
                    Kg[(((n << 3) + h) * 2048 + l) * 32 + d] = __float2bfloat16(val);
                } else if (j < 768) {
                    int e = j - 512, h = e >> 5, d = e & 31;
                    Vt[(((n << 3) + h) * 32 + d) * 2048 + l] = __float2bfloat16(val);
                } else if (j < 1024) {
                    int e = j - 768, h = e >> 5, d = e & 31;
                    Qf[(((n << 3) + h) * 2048 + l) * 32 + d] = __float2bfloat16(val * scaling);
                } else {
                    int e = j - 1024, h = e >> 5, d = e & 31;
                    Kf[(((n << 3) + h) * 2048 + l) * 32 + d] = __float2bfloat16(val);
                }
            }
        }
    }
}

// ---------------------------------------------------------------------------
// K2: agent-aware flash attention, LDS-staged + pipelined, splitS=2,
// 32 q-rows per wave (2 qh): the 12 LDS fragment reads + staged bytes per
// tile feed 2x the MFMA/softmax work vs R9; stage traffic & barrier rounds
// halve; the two independent qh chains overlap each other's latencies.
// grid 512 = 8 xcd x {2 bh, 16 qg, 2 split}; block 256 thr = 4 waves.
// LDS: K/Ks [64][40] (80B rows: b128-aligned, slot=(5*row+kg)%8 uniform ->
// conflict-free read AND write), V [32][72] (uniform too). Double-buffered,
// one barrier/tile. Swapped QK^T, PV permutation applied at K-stage time,
// fixed softmax base m=0 (exp2 domain), in-lane P->A-frag.
// Partial (O,l) -> PO/PL (f32).
// ---------------------------------------------------------------------------
__global__ __launch_bounds__(256, 2) void agent_attn(
    const __hip_bfloat16* __restrict__ Qs, const __hip_bfloat16* __restrict__ Kg,
    const __hip_bfloat16* __restrict__ Vt, const __hip_bfloat16* __restrict__ Qf,
    const __hip_bfloat16* __restrict__ Kf, const int* __restrict__ qid_g,
    const int* __restrict__ kid_g, float* __restrict__ PO, float* __restrict__ PL) {
  __shared__ __hip_bfloat16 Klds[2][64][40];
  __shared__ __hip_bfloat16 Kslds[2][64][40];
  __shared__ __hip_bfloat16 Vlds[2][32][72];

  const int tid = threadIdx.x;
  const int lane = tid & 63, w = tid >> 6;
  const int ln = lane & 15, kg = lane >> 4;

  const int flat = blockIdx.x;               // 512 = 8 xcd * (2 bh | 16 qg | 2 split)
  const int slot = flat >> 3;                // 0..63
  const int bh = ((flat & 7) << 1) | (slot & 1);
  const int rest = slot >> 1;                // 0..31
  const int qg = rest & 15, split = rest >> 4;
  const int q0 = qg * 128 + w * 32;
  const int kbase = split * 1024;

  const __hip_bfloat16* Qb  = Qs + (size_t)bh * 2048 * 32;
  const __hip_bfloat16* Qfb = Qf + (size_t)bh * 2048 * 32;
  const __hip_bfloat16* Kb  = Kg + (size_t)bh * 2048 * 32;
  const __hip_bfloat16* Ksb = Kf + (size_t)bh * 2048 * 32;
  const __hip_bfloat16* Vb  = Vt + (size_t)bh * 32 * 2048;

  // staging geometry (constant per thread)
  const int krho = tid >> 2, kseg = tid & 3;       // K/Ks: row [0,64), 4x8 bf16 segs
  const int ksub = krho >> 4, ki = krho & 15;
  // permuted global key for LDS row krho: g = (i>>2)*8 + (i&3) + off[sub]
  const int gK = ((ki >> 2) << 3) + (ki & 3) + ((ksub & 1) << 5) + ((ksub >> 1) << 2);
  const int vrow = tid >> 3, vseg = tid & 7;       // V: row [0,32), 8x8 bf16 segs

  // Q fragments (B-operand: row=q=ln, k=kg*8+j) + per-lane q identities
  short8b bQ[2], bQf[2];
  int qidq[2];
#pragma unroll
  for (int qh = 0; qh < 2; ++qh) {
    bQ[qh]  = *(const short8b*)&Qb [(q0 + qh * 16 + ln) * 32 + kg * 8];
    bQf[qh] = *(const short8b*)&Qfb[(q0 + qh * 16 + ln) * 32 + kg * 8];
    qidq[qh] = qid_g[q0 + qh * 16 + ln];
  }

  float lacc[2] = {0.f, 0.f};      // per-lane partial softmax denominators
  float4v O[2][2] = {};            // [qh][dh], layout C[q=kg*4+r][d=ln]

  // prologue: stage tile 0 into buffer 0
  {
    short8b rk = *(const short8b*)&Kb [(size_t)(kbase + gK) * 32 + kseg * 8];
    short8b rs = *(const short8b*)&Ksb[(size_t)(kbase + gK) * 32 + kseg * 8];
    short8b rv = *(const short8b*)&Vb [(size_t)vrow * 2048 + kbase + vseg * 8];
    *(short8b*)&Klds [0][krho][kseg * 8] = rk;
    *(short8b*)&Kslds[0][krho][kseg * 8] = rs;
    *(short8b*)&Vlds [0][vrow][vseg * 8] = rv;
  }
  __syncthreads();

  short8b rk, rs, rv;
#pragma unroll 1
  for (int t = 0; t < 16; ++t) {
    const int cur = t & 1;
    const int s0 = kbase + t * 64;
    // issue next tile's global loads first (latency hides under consume)
    if (t < 15) {
      const int s0n = s0 + 64;
      rk = *(const short8b*)&Kb [(size_t)(s0n + gK) * 32 + kseg * 8];
      rs = *(const short8b*)&Ksb[(size_t)(s0n + gK) * 32 + kseg * 8];
      rv = *(const short8b*)&Vb [(size_t)vrow * 2048 + s0n + vseg * 8];
    }
    // key identities for this tile (L1-resident, broadcast across lanes)
    const int* ip = kid_g + s0 + kg * 8;
    int4 t0 = *(const int4*)(ip);
    int4 t1 = *(const int4*)(ip + 32);
    int4 t2 = *(const int4*)(ip + 4);
    int4 t3 = *(const int4*)(ip + 36);
    int sd[4][4] = {{t0.x, t0.y, t0.z, t0.w}, {t1.x, t1.y, t1.z, t1.w},
                    {t2.x, t2.y, t2.z, t2.w}, {t3.x, t3.y, t3.z, t3.w}};

    // consume buf[cur]
    short8b aK[4], aS[4], bV[2][2];
#pragma unroll
    for (int sub = 0; sub < 4; ++sub) {
      aK[sub] = *(const short8b*)&Klds [cur][sub * 16 + ln][kg * 8];
      aS[sub] = *(const short8b*)&Kslds[cur][sub * 16 + ln][kg * 8];
    }
#pragma unroll
    for (int kk = 0; kk < 2; ++kk)
#pragma unroll
      for (int dh = 0; dh < 2; ++dh)
        bV[kk][dh] = *(const short8b*)&Vlds[cur][dh * 16 + ln][kk * 32 + kg * 8];

#pragma unroll
    for (int qh = 0; qh < 2; ++qh) {
      float4v ci[4], cs[4];
      float4v z = {0.f, 0.f, 0.f, 0.f};
      __builtin_amdgcn_s_setprio(1);
#pragma unroll
      for (int sub = 0; sub < 4; ++sub) {
        ci[sub] = __builtin_amdgcn_mfma_f32_16x16x32_bf16(aK[sub], bQ[qh],  z, 0, 0, 0);
        cs[sub] = __builtin_amdgcn_mfma_f32_16x16x32_bf16(aS[sub], bQf[qh], z, 0, 0, 0);
      }
      __builtin_amdgcn_s_setprio(0);
      // blend by agent identity + exp2 (fixed base, all independent)
      float p[4][4];
#pragma unroll
      for (int sub = 0; sub < 4; ++sub)
#pragma unroll
        for (int r = 0; r < 4; ++r)
          p[sub][r] = exp2f((sd[sub][r] == qidq[qh]) ? cs[sub][r] : ci[sub][r]);
      float y0 = (p[0][0] + p[0][1]) + (p[0][2] + p[0][3]);
      float y1 = (p[1][0] + p[1][1]) + (p[1][2] + p[1][3]);
      float y2 = (p[2][0] + p[2][1]) + (p[2][2] + p[2][3]);
      float y3 = (p[3][0] + p[3][1]) + (p[3][2] + p[3][3]);
      lacc[qh] += (y0 + y1) + (y2 + y3);
      // P -> PV A-fragments, fully in-lane (permutation applied at stage time)
      union { short8b v; unsigned short us[8]; } apk[2];
#pragma unroll
      for (int kk = 0; kk < 2; ++kk) {
        apk[kk].us[0] = f2bf_bits(p[kk][0]);     apk[kk].us[1] = f2bf_bits(p[kk][1]);
        apk[kk].us[2] = f2bf_bits(p[kk][2]);     apk[kk].us[3] = f2bf_bits(p[kk][3]);
        apk[kk].us[4] = f2bf_bits(p[kk + 2][0]); apk[kk].us[5] = f2bf_bits(p[kk + 2][1]);
        apk[kk].us[6] = f2bf_bits(p[kk + 2][2]); apk[kk].us[7] = f2bf_bits(p[kk + 2][3]);
      }
      __builtin_amdgcn_s_setprio(1);
#pragma unroll
      for (int kk = 0; kk < 2; ++kk) {
        O[qh][0] = __builtin_amdgcn_mfma_f32_16x16x32_bf16(apk[kk].v, bV[kk][0], O[qh][0], 0, 0, 0);
        O[qh][1] = __builtin_amdgcn_mfma_f32_16x16x32_bf16(apk[kk].v, bV[kk][1], O[qh][1], 0, 0, 0);
      }
      __builtin_amdgcn_s_setprio(0);
    }

    // write next tile into the other buffer (safe: others read buf[cur] only)
    if (t < 15) {
      *(short8b*)&Klds [cur ^ 1][krho][kseg * 8] = rk;
      *(short8b*)&Kslds[cur ^ 1][krho][kseg * 8] = rs;
      *(short8b*)&Vlds [cur ^ 1][vrow][vseg * 8] = rv;
    }
    __syncthreads();
  }

  // epilogue: per-lane l partials reduced across kg groups; write partials
  float* pob = PO + (size_t)(split * 16 + bh) * 2048 * 32;
  float* plb = PL + (size_t)(split * 16 + bh) * 2048;
#pragma unroll
  for (int qh = 0; qh < 2; ++qh) {
    float ps = lacc[qh];
    ps += __shfl_xor(ps, 16);
    ps += __shfl_xor(ps, 32);        // all lanes: l_partial for q = q0+qh*16+ln
#pragma unroll
    for (int r = 0; r < 4; ++r) {
      int q = q0 + qh * 16 + kg * 4 + r;
      pob[(size_t)q * 32 + ln]      = O[qh][0][r];
      pob[(size_t)q * 32 + 16 + ln] = O[qh][1][r];
    }
    if (kg == 0) plb[q0 + qh * 16 + ln] = ps;
  }
}

// ---------------------------------------------------------------------------
// K2b: merge splitS=2 partials -> Ab (4096 x 256 bf16). m=0 -> plain sums.
// Coalesced: 8 threads per q (wave reads 1 KB contiguous per split).
// ---------------------------------------------------------------------------
__global__ __launch_bounds__(256) void combine_splits(
    const float* __restrict__ PO, const float* __restrict__ PL,
    __hip_bfloat16* __restrict__ Ab) {
  const int blk = blockIdx.x;                 // 1024 blocks: 64 per bh
  const int bh = blk >> 6;
  const int q = ((blk & 63) << 5) | (threadIdx.x >> 3);   // 32 q per block
  const int d4 = threadIdx.x & 7;             // float4 index within 32 d
  const int n = bh >> 3, h = bh & 7;
  float L = PL[(size_t)bh * 2048 + q] + PL[(size_t)(16 + bh) * 2048 + q];
  float inv = 1.f / L;
  float4 a0 = *(const float4*)&PO[((size_t)bh * 2048 + q) * 32 + d4 * 4];
  float4 a1 = *(const float4*)&PO[((size_t)(16 + bh) * 2048 + q) * 32 + d4 * 4];
  union { ushort4 u; __hip_bfloat16 hh[4]; } o;
  o.hh[0] = __float2bfloat16((a0.x + a1.x) * inv);
  o.hh[1] = __float2bfloat16((a0.y + a1.y) * inv);
  o.hh[2] = __float2bfloat16((a0.z + a1.z) * inv);
  o.hh[3] = __float2bfloat16((a0.w + a1.w) * inv);
  *(ushort4*)&Ab[((size_t)q * 2 + n) * 256 + h * 32 + d4 * 4] = o.u;
}

// ---------------------------------------------------------------------------
// K3: out projection, 64x64 tiles. W_o converted f32->bf16 inline in staging.
// out(4096 x 256, f32) = Ab @ W_o^T + bias
// ---------------------------------------------------------------------------
__global__ __launch_bounds__(256) void out_gemm(
    const __hip_bfloat16* __restrict__ A, const float* __restrict__ Wo,
    const float* __restrict__ bias, float* __restrict__ out) {
    __shared__ __hip_bfloat16 At[64][40];
    __shared__ __hip_bfloat16 Bt[64][40];
    const int tid = threadIdx.x;
    const int lane = tid & 63, w = tid >> 6;
    const int ln = lane & 15, kg = lane >> 4;
    const int wr = w >> 1, wc = w & 1;
    const int rowBase = blockIdx.y * 64;
    const int colBase = blockIdx.x * 64;
    float4v acc[2][2] = {};

    for (int kt = 0; kt < 8; ++kt) {
        int row = tid >> 2, c = tid & 3;
        *(short8b*)&At[row][c * 8] =
            *(const short8b*)&A[(size_t)(rowBase + row) * 256 + kt * 32 + c * 8];
        float fb[8];
        *(float4*)&fb[0] = *(const float4*)&Wo[(size_t)(colBase + row) * 256 + kt * 32 + c * 8];
        *(float4*)&fb[4] = *(const float4*)&Wo[(size_t)(colBase + row) * 256 + kt * 32 + c * 8 + 4];
        *(short8b*)&Bt[row][c * 8] = cvt8(fb);
        __syncthreads();
        short8b a[2], b[2];
#pragma unroll
        for (int mi = 0; mi < 2; ++mi) a[mi] = *(const short8b*)&At[wr * 32 + mi * 16 + ln][kg * 8];
#pragma unroll
        for (int nj = 0; nj < 2; ++nj) b[nj] = *(const short8b*)&Bt[wc * 32 + nj * 16 + ln][kg * 8];
#pragma unroll
        for (int mi = 0; mi < 2; ++mi)
#pragma unroll
            for (int nj = 0; nj < 2; ++nj)
                acc[mi][nj] = __builtin_amdgcn_mfma_f32_16x16x32_bf16(a[mi], b[nj], acc[mi][nj], 0, 0, 0);
        __syncthreads();
    }

#pragma unroll
    for (int mi = 0; mi < 2; ++mi) {
#pragma unroll
        for (int nj = 0; nj < 2; ++nj) {
            int j = colBase + wc * 32 + nj * 16 + ln;
            float bj = bias[j];
#pragma unroll
            for (int r = 0; r < 4; ++r) {
                int row = rowBase + wr * 32 + mi * 16 + kg * 4 + r;
                out[row * 256 + j] = acc[mi][nj][r] + bj;
            }
        }
    }
}

// ---------------------------------------------------------------------------
extern "C" void kernel_launch(void* const* d_in, const int* in_sizes, int n_in,
                              void* d_out, int out_size, void* d_ws, size_t ws_size,
                              hipStream_t stream) {
    const float* query = (const float*)d_in[0];
    const float* W_in  = (const float*)d_in[1];
    const float* b_in  = (const float*)d_in[2];
    const float* W_s   = (const float*)d_in[3];
    const float* b_s   = (const float*)d_in[4];
    const float* W_o   = (const float*)d_in[5];
    const float* b_o   = (const float*)d_in[6];
    const int*   qids  = (const int*)d_in[7];
    const int*   kids  = (const int*)d_in[8];
    float* out = (float*)d_out;

    __hip_bfloat16* Qs  = (__hip_bfloat16*)d_ws;       // [16][2048][32]
    __hip_bfloat16* Kg  = Qs + 16 * 2048 * 32;
    __hip_bfloat16* Vt  = Kg + 16 * 2048 * 32;         // [16][32][2048]
    __hip_bfloat16* Qf  = Vt + 16 * 2048 * 32;
    __hip_bfloat16* Kf  = Qf + 16 * 2048 * 32;
    __hip_bfloat16* Ab  = Kf + 16 * 2048 * 32;         // 4096 x 256
    __hip_bfloat16* Xb  = Ab + 4096 * 256;             // 4096 x 256
    float* PO = (float*)(Xb + 4096 * 256);             // [2][16][2048][32] f32
    float* PL = PO + (size_t)2 * 16 * 2048 * 32;       // [2][16][2048] f32

    cast_X<<<1024, 256, 0, stream>>>(query, Xb);
    proj_gemm<<<dim3(20, 32), 256, 0, stream>>>(Xb, W_in, W_s, b_in, b_s,
                                                Qs, Kg, Vt, Qf, Kf);
    agent_attn<<<512, 256, 0, stream>>>(Qs, Kg, Vt, Qf, Kf, qids, kids, PO, PL);
    combine_splits<<<1024, 256, 0, stream>>>(PO, PL, Ab);
    out_gemm<<<dim3(4, 64), 256, 0, stream>>>(Ab, W_o, b_o, out);
}

// Round 15
// 64.722 us; speedup vs baseline: 3.6488x; 1.0336x over previous
//
#include <hip/hip_runtime.h>
#include <hip/hip_bf16.h>

typedef __attribute__((ext_vector_type(8))) short short8b;
typedef __attribute__((ext_vector_type(4))) float float4v;

static __device__ __forceinline__ unsigned short f2bf_bits(float f) {
  union { __hip_bfloat16 h; unsigned short u; } c;
  c.h = __float2bfloat16(f);
  return c.u;
}

static __device__ __forceinline__ short8b cvt8(const float* s) {
  union { short8b v; unsigned short us[8]; } o;
#pragma unroll
  for (int i = 0; i < 8; ++i) o.us[i] = f2bf_bits(s[i]);
  return o.v;
}

// ---------------------------------------------------------------------------
// K0: X f32 -> bf16 (proj_gemm re-reads X 20x, so pre-cast pays)
// ---------------------------------------------------------------------------
__global__ __launch_bounds__(256) void cast_X(const float* __restrict__ src,
                                              __hip_bfloat16* __restrict__ dst) {
  int i = blockIdx.x * 256 + threadIdx.x;      // 262144 float4 groups
  float4 v = reinterpret_cast<const float4*>(src)[i];
  union { ushort4 u; __hip_bfloat16 h[4]; } o;
  o.h[0] = __float2bfloat16(v.x); o.h[1] = __float2bfloat16(v.y);
  o.h[2] = __float2bfloat16(v.z); o.h[3] = __float2bfloat16(v.w);
  reinterpret_cast<ushort4*>(dst)[i] = o.u;
}

// ---------------------------------------------------------------------------
// K1: projection GEMM (R9 version). C(4096 x 1280) = Xb @ W^T, 128x64 tiles.
// W f32 converted in staging. Q-scaling includes log2(e). Epilogue scatters
// per-head: Qs,K,Qf,Kf : [bh][2048][32]    V -> Vt : [bh][32][2048]
// ---------------------------------------------------------------------------
__global__ __launch_bounds__(256) void proj_gemm(
    const __hip_bfloat16* __restrict__ Xb, const float* __restrict__ W1,
    const float* __restrict__ W2,
    const float* __restrict__ bias, const float* __restrict__ bias_s,
    __hip_bfloat16* __restrict__ Qs, __hip_bfloat16* __restrict__ Kg,
    __hip_bfloat16* __restrict__ Vt, __hip_bfloat16* __restrict__ Qf,
    __hip_bfloat16* __restrict__ Kf) {
    __shared__ __hip_bfloat16 At[128][40];
    __shared__ __hip_bfloat16 Bt[64][40];
    const int tid = threadIdx.x;
    const int lane = tid & 63, w = tid >> 6;
    const int ln = lane & 15, kg = lane >> 4;
    const int wr = w >> 1, wc = w & 1;
    const int rowBase = blockIdx.y * 128;
    const int colBase = blockIdx.x * 64;
    const float* Wsrc = (colBase < 768) ? (W1 + (size_t)colBase * 256)
                                        : (W2 + (size_t)(colBase - 768) * 256);
    float4v acc[4][2] = {};

    for (int kt = 0; kt < 8; ++kt) {
        int cid = tid;
#pragma unroll
        for (int p = 0; p < 2; ++p, cid += 256) {
            int row = cid >> 2, c = cid & 3;
            *(short8b*)&At[row][c * 8] =
                *(const short8b*)&Xb[(size_t)(rowBase + row) * 256 + kt * 32 + c * 8];
        }
        {
            int row = tid >> 2, c = tid & 3;
            float fb[8];
            *(float4*)&fb[0] = *(const float4*)&Wsrc[(size_t)row * 256 + kt * 32 + c * 8];
            *(float4*)&fb[4] = *(const float4*)&Wsrc[(size_t)row * 256 + kt * 32 + c * 8 + 4];
            *(short8b*)&Bt[row][c * 8] = cvt8(fb);
        }
        __syncthreads();
        short8b a[4], b[2];
#pragma unroll
        for (int mi = 0; mi < 4; ++mi) a[mi] = *(const short8b*)&At[wr * 64 + mi * 16 + ln][kg * 8];
#pragma unroll
        for (int nj = 0; nj < 2; ++nj) b[nj] = *(const short8b*)&Bt[wc * 32 + nj * 16 + ln][kg * 8];
#pragma unroll
        for (int mi = 0; mi < 4; ++mi)
#pragma unroll
            for (int nj = 0; nj < 2; ++nj)
                acc[mi][nj] = __builtin_amdgcn_mfma_f32_16x16x32_bf16(a[mi], b[nj], acc[mi][nj], 0, 0, 0);
        __syncthreads();
    }

    const float scaling = 0.17677669529663687f * 1.4426950408889634f;  // 32^-0.5 * log2(e)
#pragma unroll
    for (int mi = 0; mi < 4; ++mi) {
#pragma unroll
        for (int nj = 0; nj < 2; ++nj) {
            int j = colBase + wc * 32 + nj * 16 + ln;
            float bj = (j < 768) ? bias[j] : bias_s[j - 768];
#pragma unroll
            for (int r = 0; r < 4; ++r) {
                int row = rowBase + wr * 64 + mi * 16 + kg * 4 + r;
                float val = acc[mi][nj][r] + bj;
                int l = row >> 1, n = row & 1;
                if (j < 256) {
                    int h = j >> 5, d = j & 31;
                    Qs[(((n << 3) + h) * 2048 + l) * 32 + d] = __float2bfloat16(val * scaling);
                } else if (j < 512) {
                    int e = j - 256, h = e >> 5, d = e & 31;
                    Kg[(((n << 3) + h) * 2048 + l) * 32 + d] = __float2bfloat16(val);
                } else if (j < 768) {
                    int e = j - 512, h = e >> 5, d = e & 31;
                    Vt[(((n << 3) + h) * 32 + d) * 2048 + l] = __float2bfloat16(val);
                } else if (j < 1024) {
                    int e = j - 768, h = e >> 5, d = e & 31;
                    Qf[(((n << 3) + h) * 2048 + l) * 32 + d] = __float2bfloat16(val * scaling);
                } else {
                    int e = j - 1024, h = e >> 5, d = e & 31;
                    Kf[(((n << 3) + h) * 2048 + l) * 32 + d] = __float2bfloat16(val);
                }
            }
        }
    }
}

// ---------------------------------------------------------------------------
// K2: agent-aware flash attention, LDS-staged + pipelined, splitS=2.
// Exactly the R9 winner, with ONE change: K/Ks LDS rows padded 36 -> 40
// elements (80B rows: b128-aligned, bank slot (5*row+kg)%8 uniform ->
// conflict-free stage-write AND fragment-read; R8/R13 counters showed
// 1-2M conflict cycles with the 72B rows).
// grid 1024 = 8 xcd x {2 bh, 32 qg, 2 split}; block 256 thr = 4 waves x 16 q.
// Per tile: K/Ks staged with the PV permutation applied at stage time,
// V in [32][72]; double-buffered; one barrier/tile. Swapped QK^T, fixed
// softmax base m=0 (exp2 domain), in-lane P->A-frag, PV.
// Partial (O,l) -> PO/PL (f32).
// ---------------------------------------------------------------------------
__global__ __launch_bounds__(256, 2) void agent_attn(
    const __hip_bfloat16* __restrict__ Qs, const __hip_bfloat16* __restrict__ Kg,
    const __hip_bfloat16* __restrict__ Vt, const __hip_bfloat16* __restrict__ Qf,
    const __hip_bfloat16* __restrict__ Kf, const int* __restrict__ qid_g,
    const int* __restrict__ kid_g, float* __restrict__ PO, float* __restrict__ PL) {
  __shared__ __hip_bfloat16 Klds[2][64][40];
  __shared__ __hip_bfloat16 Kslds[2][64][40];
  __shared__ __hip_bfloat16 Vlds[2][32][72];

  const int tid = threadIdx.x;
  const int lane = tid & 63, w = tid >> 6;
  const int ln = lane & 15, kg = lane >> 4;

  const int flat = blockIdx.x;               // 1024 = 8 xcd * (2 bh | 32 qg | 2 split)
  const int slot = flat >> 3;
  const int bh = ((flat & 7) << 1) | (slot & 1);
  const int rest = slot >> 1;                // 0..63
  const int qg = rest & 31, split = rest >> 5;
  const int q0 = qg * 64 + w * 16;
  const int kbase = split * 1024;

  const __hip_bfloat16* Qb  = Qs + (size_t)bh * 2048 * 32;
  const __hip_bfloat16* Qfb = Qf + (size_t)bh * 2048 * 32;
  const __hip_bfloat16* Kb  = Kg + (size_t)bh * 2048 * 32;
  const __hip_bfloat16* Ksb = Kf + (size_t)bh * 2048 * 32;
  const __hip_bfloat16* Vb  = Vt + (size_t)bh * 32 * 2048;

  // staging geometry (constant per thread)
  const int krho = tid >> 2, kseg = tid & 3;       // K/Ks: row [0,64), 4x8 bf16 segs
  const int ksub = krho >> 4, ki = krho & 15;
  // permuted global key for LDS row krho: g = (i>>2)*8 + (i&3) + off[sub]
  const int gK = ((ki >> 2) << 3) + (ki & 3) + ((ksub & 1) << 5) + ((ksub >> 1) << 2);
  const int vrow = tid >> 3, vseg = tid & 7;       // V: row [0,32), 8x8 bf16 segs

  // Q fragments (B-operand: row=q=ln, k=kg*8+j) + per-lane q identity
  short8b bQ  = *(const short8b*)&Qb [(q0 + ln) * 32 + kg * 8];
  short8b bQf = *(const short8b*)&Qfb[(q0 + ln) * 32 + kg * 8];
  const int qidq = qid_g[q0 + ln];

  float lacc = 0.f;                // per-lane partial softmax denominator
  float4v O0 = {0.f, 0.f, 0.f, 0.f}, O1 = {0.f, 0.f, 0.f, 0.f};

  // prologue: stage tile 0 into buffer 0
  {
    short8b rk = *(const short8b*)&Kb [(size_t)(kbase + gK) * 32 + kseg * 8];
    short8b rs = *(const short8b*)&Ksb[(size_t)(kbase + gK) * 32 + kseg * 8];
    short8b rv = *(const short8b*)&Vb [(size_t)vrow * 2048 + kbase + vseg * 8];
    *(short8b*)&Klds [0][krho][kseg * 8] = rk;
    *(short8b*)&Kslds[0][krho][kseg * 8] = rs;
    *(short8b*)&Vlds [0][vrow][vseg * 8] = rv;
  }
  __syncthreads();

  short8b rk, rs, rv;
#pragma unroll 1
  for (int t = 0; t < 16; ++t) {
    const int cur = t & 1;
    const int s0 = kbase + t * 64;
    // issue next tile's global loads first (latency hides under consume)
    if (t < 15) {
      const int s0n = s0 + 64;
      rk = *(const short8b*)&Kb [(size_t)(s0n + gK) * 32 + kseg * 8];
      rs = *(const short8b*)&Ksb[(size_t)(s0n + gK) * 32 + kseg * 8];
      rv = *(const short8b*)&Vb [(size_t)vrow * 2048 + s0n + vseg * 8];
    }
    // key identities for this tile (L1-resident, broadcast across lanes)
    const int* ip = kid_g + s0 + kg * 8;
    int4 t0 = *(const int4*)(ip);
    int4 t1 = *(const int4*)(ip + 32);
    int4 t2 = *(const int4*)(ip + 4);
    int4 t3 = *(const int4*)(ip + 36);
    int sd[4][4] = {{t0.x, t0.y, t0.z, t0.w}, {t1.x, t1.y, t1.z, t1.w},
                    {t2.x, t2.y, t2.z, t2.w}, {t3.x, t3.y, t3.z, t3.w}};

    // consume buf[cur]
    short8b aK[4], aS[4], bV[2][2];
#pragma unroll
    for (int sub = 0; sub < 4; ++sub) {
      aK[sub] = *(const short8b*)&Klds [cur][sub * 16 + ln][kg * 8];
      aS[sub] = *(const short8b*)&Kslds[cur][sub * 16 + ln][kg * 8];
    }
#pragma unroll
    for (int kk = 0; kk < 2; ++kk)
#pragma unroll
      for (int dh = 0; dh < 2; ++dh)
        bV[kk][dh] = *(const short8b*)&Vlds[cur][dh * 16 + ln][kk * 32 + kg * 8];

    float4v ci[4], cs[4];
    float4v z = {0.f, 0.f, 0.f, 0.f};
    __builtin_amdgcn_s_setprio(1);
#pragma unroll
    for (int sub = 0; sub < 4; ++sub) {
      ci[sub] = __builtin_amdgcn_mfma_f32_16x16x32_bf16(aK[sub], bQ,  z, 0, 0, 0);
      cs[sub] = __builtin_amdgcn_mfma_f32_16x16x32_bf16(aS[sub], bQf, z, 0, 0, 0);
    }
    __builtin_amdgcn_s_setprio(0);
    // blend by agent identity + exp2 (fixed base, all independent)
    float p[4][4];
#pragma unroll
    for (int sub = 0; sub < 4; ++sub)
#pragma unroll
      for (int r = 0; r < 4; ++r)
        p[sub][r] = exp2f((sd[sub][r] == qidq) ? cs[sub][r] : ci[sub][r]);
    float y0 = (p[0][0] + p[0][1]) + (p[0][2] + p[0][3]);
    float y1 = (p[1][0] + p[1][1]) + (p[1][2] + p[1][3]);
    float y2 = (p[2][0] + p[2][1]) + (p[2][2] + p[2][3]);
    float y3 = (p[3][0] + p[3][1]) + (p[3][2] + p[3][3]);
    lacc += (y0 + y1) + (y2 + y3);
    // P -> PV A-fragments, fully in-lane (permutation applied at stage time)
    union { short8b v; unsigned short us[8]; } apk[2];
#pragma unroll
    for (int kk = 0; kk < 2; ++kk) {
      apk[kk].us[0] = f2bf_bits(p[kk][0]);     apk[kk].us[1] = f2bf_bits(p[kk][1]);
      apk[kk].us[2] = f2bf_bits(p[kk][2]);     apk[kk].us[3] = f2bf_bits(p[kk][3]);
      apk[kk].us[4] = f2bf_bits(p[kk + 2][0]); apk[kk].us[5] = f2bf_bits(p[kk + 2][1]);
      apk[kk].us[6] = f2bf_bits(p[kk + 2][2]); apk[kk].us[7] = f2bf_bits(p[kk + 2][3]);
    }
    __builtin_amdgcn_s_setprio(1);
#pragma unroll
    for (int kk = 0; kk < 2; ++kk) {
      O0 = __builtin_amdgcn_mfma_f32_16x16x32_bf16(apk[kk].v, bV[kk][0], O0, 0, 0, 0);
      O1 = __builtin_amdgcn_mfma_f32_16x16x32_bf16(apk[kk].v, bV[kk][1], O1, 0, 0, 0);
    }
    __builtin_amdgcn_s_setprio(0);

    // write next tile into the other buffer (safe: others read buf[cur] only)
    if (t < 15) {
      *(short8b*)&Klds [cur ^ 1][krho][kseg * 8] = rk;
      *(short8b*)&Kslds[cur ^ 1][krho][kseg * 8] = rs;
      *(short8b*)&Vlds [cur ^ 1][vrow][vseg * 8] = rv;
    }
    __syncthreads();
  }

  // epilogue: per-lane l partial reduced across kg groups; write partials
  float ps = lacc;
  ps += __shfl_xor(ps, 16);
  ps += __shfl_xor(ps, 32);          // all lanes: l_partial for q = q0 + ln
  float* pob = PO + (size_t)(split * 16 + bh) * 2048 * 32;
  float* plb = PL + (size_t)(split * 16 + bh) * 2048;
#pragma unroll
  for (int r = 0; r < 4; ++r) {
    int q = q0 + kg * 4 + r;
    pob[(size_t)q * 32 + ln]      = O0[r];
    pob[(size_t)q * 32 + 16 + ln] = O1[r];
  }
  if (kg == 0) plb[q0 + ln] = ps;
}

// ---------------------------------------------------------------------------
// K2b: merge splitS=2 partials -> Ab (4096 x 256 bf16). m=0 -> plain sums.
// Coalesced: 8 threads per q (wave reads 1 KB contiguous per split).
// ---------------------------------------------------------------------------
__global__ __launch_bounds__(256) void combine_splits(
    const float* __restrict__ PO, const float* __restrict__ PL,
    __hip_bfloat16* __restrict__ Ab) {
  const int blk = blockIdx.x;                 // 1024 blocks: 64 per bh
  const int bh = blk >> 6;
  const int q = ((blk & 63) << 5) | (threadIdx.x >> 3);   // 32 q per block
  const int d4 = threadIdx.x & 7;             // float4 index within 32 d
  const int n = bh >> 3, h = bh & 7;
  float L = PL[(size_t)bh * 2048 + q] + PL[(size_t)(16 + bh) * 2048 + q];
  float inv = 1.f / L;
  float4 a0 = *(const float4*)&PO[((size_t)bh * 2048 + q) * 32 + d4 * 4];
  float4 a1 = *(const float4*)&PO[((size_t)(16 + bh) * 2048 + q) * 32 + d4 * 4];
  union { ushort4 u; __hip_bfloat16 hh[4]; } o;
  o.hh[0] = __float2bfloat16((a0.x + a1.x) * inv);
  o.hh[1] = __float2bfloat16((a0.y + a1.y) * inv);
  o.hh[2] = __float2bfloat16((a0.z + a1.z) * inv);
  o.hh[3] = __float2bfloat16((a0.w + a1.w) * inv);
  *(ushort4*)&Ab[((size_t)q * 2 + n) * 256 + h * 32 + d4 * 4] = o.u;
}

// ---------------------------------------------------------------------------
// K3: out projection, 64x64 tiles. W_o converted f32->bf16 inline in staging.
// out(4096 x 256, f32) = Ab @ W_o^T + bias
// ---------------------------------------------------------------------------
__global__ __launch_bounds__(256) void out_gemm(
    const __hip_bfloat16* __restrict__ A, const float* __restrict__ Wo,
    const float* __restrict__ bias, float* __restrict__ out) {
    __shared__ __hip_bfloat16 At[64][40];
    __shared__ __hip_bfloat16 Bt[64][40];
    const int tid = threadIdx.x;
    const int lane = tid & 63, w = tid >> 6;
    const int ln = lane & 15, kg = lane >> 4;
    const int wr = w >> 1, wc = w & 1;
    const int rowBase = blockIdx.y * 64;
    const int colBase = blockIdx.x * 64;
    float4v acc[2][2] = {};

    for (int kt = 0; kt < 8; ++kt) {
        int row = tid >> 2, c = tid & 3;
        *(short8b*)&At[row][c * 8] =
            *(const short8b*)&A[(size_t)(rowBase + row) * 256 + kt * 32 + c * 8];
        float fb[8];
        *(float4*)&fb[0] = *(const float4*)&Wo[(size_t)(colBase + row) * 256 + kt * 32 + c * 8];
        *(float4*)&fb[4] = *(const float4*)&Wo[(size_t)(colBase + row) * 256 + kt * 32 + c * 8 + 4];
        *(short8b*)&Bt[row][c * 8] = cvt8(fb);
        __syncthreads();
        short8b a[2], b[2];
#pragma unroll
        for (int mi = 0; mi < 2; ++mi) a[mi] = *(const short8b*)&At[wr * 32 + mi * 16 + ln][kg * 8];
#pragma unroll
        for (int nj = 0; nj < 2; ++nj) b[nj] = *(const short8b*)&Bt[wc * 32 + nj * 16 + ln][kg * 8];
#pragma unroll
        for (int mi = 0; mi < 2; ++mi)
#pragma unroll
            for (int nj = 0; nj < 2; ++nj)
                acc[mi][nj] = __builtin_amdgcn_mfma_f32_16x16x32_bf16(a[mi], b[nj], acc[mi][nj], 0, 0, 0);
        __syncthreads();
    }

#pragma unroll
    for (int mi = 0; mi < 2; ++mi) {
#pragma unroll
        for (int nj = 0; nj < 2; ++nj) {
            int j = colBase + wc * 32 + nj * 16 + ln;
            float bj = bias[j];
#pragma unroll
            for (int r = 0; r < 4; ++r) {
                int row = rowBase + wr * 32 + mi * 16 + kg * 4 + r;
                out[row * 256 + j] = acc[mi][nj][r] + bj;
            }
        }
    }
}

// ---------------------------------------------------------------------------
extern "C" void kernel_launch(void* const* d_in, const int* in_sizes, int n_in,
                              void* d_out, int out_size, void* d_ws, size_t ws_size,
                              hipStream_t stream) {
    const float* query = (const float*)d_in[0];
    const float* W_in  = (const float*)d_in[1];
    const float* b_in  = (const float*)d_in[2];
    const float* W_s   = (const float*)d_in[3];
    const float* b_s   = (const float*)d_in[4];
    const float* W_o   = (const float*)d_in[5];
    const float* b_o   = (const float*)d_in[6];
    const int*   qids  = (const int*)d_in[7];
    const int*   kids  = (const int*)d_in[8];
    float* out = (float*)d_out;

    __hip_bfloat16* Qs  = (__hip_bfloat16*)d_ws;       // [16][2048][32]
    __hip_bfloat16* Kg  = Qs + 16 * 2048 * 32;
    __hip_bfloat16* Vt  = Kg + 16 * 2048 * 32;         // [16][32][2048]
    __hip_bfloat16* Qf  = Vt + 16 * 2048 * 32;
    __hip_bfloat16* Kf  = Qf + 16 * 2048 * 32;
    __hip_bfloat16* Ab  = Kf + 16 * 2048 * 32;         // 4096 x 256
    __hip_bfloat16* Xb  = Ab + 4096 * 256;             // 4096 x 256
    float* PO = (float*)(Xb + 4096 * 256);             // [2][16][2048][32] f32
    float* PL = PO + (size_t)2 * 16 * 2048 * 32;       // [2][16][2048] f32

    cast_X<<<1024, 256, 0, stream>>>(query, Xb);
    proj_gemm<<<dim3(20, 32), 256, 0, stream>>>(Xb, W_in, W_s, b_in, b_s,
                                                Qs, Kg, Vt, Qf, Kf);
    agent_attn<<<1024, 256, 0, stream>>>(Qs, Kg, Vt, Qf, Kf, qids, kids, PO, PL);
    combine_splits<<<1024, 256, 0, stream>>>(PO, PL, Ab);
    out_gemm<<<dim3(4, 64), 256, 0, stream>>>(Ab, W_o, b_o, out);
}

// Round 16
// 59.952 us; speedup vs baseline: 3.9390x; 1.0796x over previous
//
#include <hip/hip_runtime.h>
#include <hip/hip_bf16.h>

typedef __attribute__((ext_vector_type(8))) short short8b;
typedef __attribute__((ext_vector_type(4))) float float4v;

static __device__ __forceinline__ unsigned short f2bf_bits(float f) {
  union { __hip_bfloat16 h; unsigned short u; } c;
  c.h = __float2bfloat16(f);
  return c.u;
}

// ---------------------------------------------------------------------------
// K0: fused f32 -> bf16 cast: query + W_in + W_s + W_o.
// [query 262144 | W_in 49152 | W_s 32768 | W_o 16384] float4 groups.
// Removes f32 weight re-reads (32-64x per col-block) + cvt VALU from the
// GEMM staging critical paths.
// ---------------------------------------------------------------------------
__global__ __launch_bounds__(256) void cast_all(
    const float* __restrict__ q, const float* __restrict__ w1,
    const float* __restrict__ w2, const float* __restrict__ w3,
    __hip_bfloat16* __restrict__ Xb, __hip_bfloat16* __restrict__ Wb,
    __hip_bfloat16* __restrict__ Wob) {
  int i = blockIdx.x * blockDim.x + threadIdx.x;
  if (i >= 360448) return;
  const float* src; __hip_bfloat16* dst; int j;
  if (i < 262144)      { src = q;  dst = Xb;          j = i; }
  else if (i < 311296) { src = w1; dst = Wb;          j = i - 262144; }
  else if (i < 344064) { src = w2; dst = Wb + 196608; j = i - 311296; }
  else                 { src = w3; dst = Wob;         j = i - 344064; }
  float4 v = reinterpret_cast<const float4*>(src)[j];
  union { ushort4 u; __hip_bfloat16 h[4]; } o;
  o.h[0] = __float2bfloat16(v.x); o.h[1] = __float2bfloat16(v.y);
  o.h[2] = __float2bfloat16(v.z); o.h[3] = __float2bfloat16(v.w);
  reinterpret_cast<ushort4*>(dst)[j] = o.u;
}

// ---------------------------------------------------------------------------
// K1: projection GEMM. C(4096 x 1280) = Xb @ Wb^T, 128x64 tiles, all bf16
// staging (no inline conversion). Q-scaling includes log2(e). Epilogue
// scatters per-head: Qs,K,Qf,Kf : [bh][2048][32]   V -> Vt : [bh][32][2048]
// ---------------------------------------------------------------------------
__global__ __launch_bounds__(256) void proj_gemm(
    const __hip_bfloat16* __restrict__ Xb, const __hip_bfloat16* __restrict__ Wb,
    const float* __restrict__ bias, const float* __restrict__ bias_s,
    __hip_bfloat16* __restrict__ Qs, __hip_bfloat16* __restrict__ Kg,
    __hip_bfloat16* __restrict__ Vt, __hip_bfloat16* __restrict__ Qf,
    __hip_bfloat16* __restrict__ Kf) {
    __shared__ __hip_bfloat16 At[128][40];
    __shared__ __hip_bfloat16 Bt[64][40];
    const int tid = threadIdx.x;
    const int lane = tid & 63, w = tid >> 6;
    const int ln = lane & 15, kg = lane >> 4;
    const int wr = w >> 1, wc = w & 1;
    const int rowBase = blockIdx.y * 128;
    const int colBase = blockIdx.x * 64;
    const __hip_bfloat16* Wsrc = Wb + (size_t)colBase * 256;
    float4v acc[4][2] = {};

    for (int kt = 0; kt < 8; ++kt) {
        int cid = tid;
#pragma unroll
        for (int p = 0; p < 2; ++p, cid += 256) {
            int row = cid >> 2, c = cid & 3;
            *(short8b*)&At[row][c * 8] =
                *(const short8b*)&Xb[(size_t)(rowBase + row) * 256 + kt * 32 + c * 8];
        }
        {
            int row = tid >> 2, c = tid & 3;
            *(short8b*)&Bt[row][c * 8] =
                *(const short8b*)&Wsrc[(size_t)row * 256 + kt * 32 + c * 8];
        }
        __syncthreads();
        short8b a[4], b[2];
#pragma unroll
        for (int mi = 0; mi < 4; ++mi) a[mi] = *(const short8b*)&At[wr * 64 + mi * 16 + ln][kg * 8];
#pragma unroll
        for (int nj = 0; nj < 2; ++nj) b[nj] = *(const short8b*)&Bt[wc * 32 + nj * 16 + ln][kg * 8];
#pragma unroll
        for (int mi = 0; mi < 4; ++mi)
#pragma unroll
            for (int nj = 0; nj < 2; ++nj)
                acc[mi][nj] = __builtin_amdgcn_mfma_f32_16x16x32_bf16(a[mi], b[nj], acc[mi][nj], 0, 0, 0);
        __syncthreads();
    }

    const float scaling = 0.17677669529663687f * 1.4426950408889634f;  // 32^-0.5 * log2(e)
#pragma unroll
    for (int mi = 0; mi < 4; ++mi) {
#pragma unroll
        for (int nj = 0; nj < 2; ++nj) {
            int j = colBase + wc * 32 + nj * 16 + ln;
            float bj = (j < 768) ? bias[j] : bias_s[j - 768];
#pragma unroll
            for (int r = 0; r < 4; ++r) {
                int row = rowBase + wr * 64 + mi * 16 + kg * 4 + r;
                float val = acc[mi][nj][r] + bj;
                int l = row >> 1, n = row & 1;
                if (j < 256) {
                    int h = j >> 5, d = j & 31;
                    Qs[(((n << 3) + h) * 2048 + l) * 32 + d] = __float2bfloat16(val * scaling);
                } else if (j < 512) {
                    int e = j - 256, h = e >> 5, d = e & 31;
                    Kg[(((n << 3) + h) * 2048 + l) * 32 + d] = __float2bfloat16(val);
                } else if (j < 768) {
                    int e = j - 512, h = e >> 5, d = e & 31;
                    Vt[(((n << 3) + h) * 32 + d) * 2048 + l] = __float2bfloat16(val);
                } else if (j < 1024) {
                    int e = j - 768, h = e >> 5, d = e & 31;
                    Qf[(((n << 3) + h) * 2048 + l) * 32 + d] = __float2bfloat16(val * scaling);
                } else {
                    int e = j - 1024, h = e >> 5, d = e & 31;
                    Kf[(((n << 3) + h) * 2048 + l) * 32 + d] = __float2bfloat16(val);
                }
            }
        }
    }
}

// ---------------------------------------------------------------------------
// K2: agent-aware flash attention, LDS-staged + pipelined, splitS=2.
// R15 structure ([64][40] padded K/Ks, V [32][72], double-buffered, one
// barrier/tile, swapped QK^T, PV permutation at stage time, fixed softmax
// base m=0 exp2 domain, in-lane P->A-frag).
// THIS ROUND: partial O written bf16 (POb) -- halves partial traffic;
// PL stays f32.
// grid 1024 = 8 xcd x {2 bh, 32 qg, 2 split}; block 256 thr = 4 waves x 16 q.
// ---------------------------------------------------------------------------
__global__ __launch_bounds__(256, 2) void agent_attn(
    const __hip_bfloat16* __restrict__ Qs, const __hip_bfloat16* __restrict__ Kg,
    const __hip_bfloat16* __restrict__ Vt, const __hip_bfloat16* __restrict__ Qf,
    const __hip_bfloat16* __restrict__ Kf, const int* __restrict__ qid_g,
    const int* __restrict__ kid_g, __hip_bfloat16* __restrict__ POb,
    float* __restrict__ PL) {
  __shared__ __hip_bfloat16 Klds[2][64][40];
  __shared__ __hip_bfloat16 Kslds[2][64][40];
  __shared__ __hip_bfloat16 Vlds[2][32][72];

  const int tid = threadIdx.x;
  const int lane = tid & 63, w = tid >> 6;
  const int ln = lane & 15, kg = lane >> 4;

  const int flat = blockIdx.x;               // 1024 = 8 xcd * (2 bh | 32 qg | 2 split)
  const int slot = flat >> 3;
  const int bh = ((flat & 7) << 1) | (slot & 1);
  const int rest = slot >> 1;                // 0..63
  const int qg = rest & 31, split = rest >> 5;
  const int q0 = qg * 64 + w * 16;
  const int kbase = split * 1024;

  const __hip_bfloat16* Qb  = Qs + (size_t)bh * 2048 * 32;
  const __hip_bfloat16* Qfb = Qf + (size_t)bh * 2048 * 32;
  const __hip_bfloat16* Kb  = Kg + (size_t)bh * 2048 * 32;
  const __hip_bfloat16* Ksb = Kf + (size_t)bh * 2048 * 32;
  const __hip_bfloat16* Vb  = Vt + (size_t)bh * 32 * 2048;

  // staging geometry (constant per thread)
  const int krho = tid >> 2, kseg = tid & 3;       // K/Ks: row [0,64), 4x8 bf16 segs
  const int ksub = krho >> 4, ki = krho & 15;
  // permuted global key for LDS row krho: g = (i>>2)*8 + (i&3) + off[sub]
  const int gK = ((ki >> 2) << 3) + (ki & 3) + ((ksub & 1) << 5) + ((ksub >> 1) << 2);
  const int vrow = tid >> 3, vseg = tid & 7;       // V: row [0,32), 8x8 bf16 segs

  // Q fragments (B-operand: row=q=ln, k=kg*8+j) + per-lane q identity
  short8b bQ  = *(const short8b*)&Qb [(q0 + ln) * 32 + kg * 8];
  short8b bQf = *(const short8b*)&Qfb[(q0 + ln) * 32 + kg * 8];
  const int qidq = qid_g[q0 + ln];

  float lacc = 0.f;                // per-lane partial softmax denominator
  float4v O0 = {0.f, 0.f, 0.f, 0.f}, O1 = {0.f, 0.f, 0.f, 0.f};

  // prologue: stage tile 0 into buffer 0
  {
    short8b rk = *(const short8b*)&Kb [(size_t)(kbase + gK) * 32 + kseg * 8];
    short8b rs = *(const short8b*)&Ksb[(size_t)(kbase + gK) * 32 + kseg * 8];
    short8b rv = *(const short8b*)&Vb [(size_t)vrow * 2048 + kbase + vseg * 8];
    *(short8b*)&Klds [0][krho][kseg * 8] = rk;
    *(short8b*)&Kslds[0][krho][kseg * 8] = rs;
    *(short8b*)&Vlds [0][vrow][vseg * 8] = rv;
  }
  __syncthreads();

  short8b rk, rs, rv;
#pragma unroll 1
  for (int t = 0; t < 16; ++t) {
    const int cur = t & 1;
    const int s0 = kbase + t * 64;
    // issue next tile's global loads first (latency hides under consume)
    if (t < 15) {
      const int s0n = s0 + 64;
      rk = *(const short8b*)&Kb [(size_t)(s0n + gK) * 32 + kseg * 8];
      rs = *(const short8b*)&Ksb[(size_t)(s0n + gK) * 32 + kseg * 8];
      rv = *(const short8b*)&Vb [(size_t)vrow * 2048 + s0n + vseg * 8];
    }
    // key identities for this tile (L1-resident, broadcast across lanes)
    const int* ip = kid_g + s0 + kg * 8;
    int4 t0 = *(const int4*)(ip);
    int4 t1 = *(const int4*)(ip + 32);
    int4 t2 = *(const int4*)(ip + 4);
    int4 t3 = *(const int4*)(ip + 36);
    int sd[4][4] = {{t0.x, t0.y, t0.z, t0.w}, {t1.x, t1.y, t1.z, t1.w},
                    {t2.x, t2.y, t2.z, t2.w}, {t3.x, t3.y, t3.z, t3.w}};

    // consume buf[cur]
    short8b aK[4], aS[4], bV[2][2];
#pragma unroll
    for (int sub = 0; sub < 4; ++sub) {
      aK[sub] = *(const short8b*)&Klds [cur][sub * 16 + ln][kg * 8];
      aS[sub] = *(const short8b*)&Kslds[cur][sub * 16 + ln][kg * 8];
    }
#pragma unroll
    for (int kk = 0; kk < 2; ++kk)
#pragma unroll
      for (int dh = 0; dh < 2; ++dh)
        bV[kk][dh] = *(const short8b*)&Vlds[cur][dh * 16 + ln][kk * 32 + kg * 8];

    float4v ci[4], cs[4];
    float4v z = {0.f, 0.f, 0.f, 0.f};
    __builtin_amdgcn_s_setprio(1);
#pragma unroll
    for (int sub = 0; sub < 4; ++sub) {
      ci[sub] = __builtin_amdgcn_mfma_f32_16x16x32_bf16(aK[sub], bQ,  z, 0, 0, 0);
      cs[sub] = __builtin_amdgcn_mfma_f32_16x16x32_bf16(aS[sub], bQf, z, 0, 0, 0);
    }
    __builtin_amdgcn_s_setprio(0);
    // blend by agent identity + exp2 (fixed base, all independent)
    float p[4][4];
#pragma unroll
    for (int sub = 0; sub < 4; ++sub)
#pragma unroll
      for (int r = 0; r < 4; ++r)
        p[sub][r] = exp2f((sd[sub][r] == qidq) ? cs[sub][r] : ci[sub][r]);
    float y0 = (p[0][0] + p[0][1]) + (p[0][2] + p[0][3]);
    float y1 = (p[1][0] + p[1][1]) + (p[1][2] + p[1][3]);
    float y2 = (p[2][0] + p[2][1]) + (p[2][2] + p[2][3]);
    float y3 = (p[3][0] + p[3][1]) + (p[3][2] + p[3][3]);
    lacc += (y0 + y1) + (y2 + y3);
    // P -> PV A-fragments, fully in-lane (permutation applied at stage time)
    union { short8b v; unsigned short us[8]; } apk[2];
#pragma unroll
    for (int kk = 0; kk < 2; ++kk) {
      apk[kk].us[0] = f2bf_bits(p[kk][0]);     apk[kk].us[1] = f2bf_bits(p[kk][1]);
      apk[kk].us[2] = f2bf_bits(p[kk][2]);     apk[kk].us[3] = f2bf_bits(p[kk][3]);
      apk[kk].us[4] = f2bf_bits(p[kk + 2][0]); apk[kk].us[5] = f2bf_bits(p[kk + 2][1]);
      apk[kk].us[6] = f2bf_bits(p[kk + 2][2]); apk[kk].us[7] = f2bf_bits(p[kk + 2][3]);
    }
    __builtin_amdgcn_s_setprio(1);
#pragma unroll
    for (int kk = 0; kk < 2; ++kk) {
      O0 = __builtin_amdgcn_mfma_f32_16x16x32_bf16(apk[kk].v, bV[kk][0], O0, 0, 0, 0);
      O1 = __builtin_amdgcn_mfma_f32_16x16x32_bf16(apk[kk].v, bV[kk][1], O1, 0, 0, 0);
    }
    __builtin_amdgcn_s_setprio(0);

    // write next tile into the other buffer (safe: others read buf[cur] only)
    if (t < 15) {
      *(short8b*)&Klds [cur ^ 1][krho][kseg * 8] = rk;
      *(short8b*)&Kslds[cur ^ 1][krho][kseg * 8] = rs;
      *(short8b*)&Vlds [cur ^ 1][vrow][vseg * 8] = rv;
    }
    __syncthreads();
  }

  // epilogue: per-lane l partial reduced across kg groups; write partials
  float ps = lacc;
  ps += __shfl_xor(ps, 16);
  ps += __shfl_xor(ps, 32);          // all lanes: l_partial for q = q0 + ln
  __hip_bfloat16* pob = POb + (size_t)(split * 16 + bh) * 2048 * 32;
  float* plb = PL + (size_t)(split * 16 + bh) * 2048;
#pragma unroll
  for (int r = 0; r < 4; ++r) {
    int q = q0 + kg * 4 + r;
    pob[(size_t)q * 32 + ln]      = __float2bfloat16(O0[r]);
    pob[(size_t)q * 32 + 16 + ln] = __float2bfloat16(O1[r]);
  }
  if (kg == 0) plb[q0 + ln] = ps;
}

// ---------------------------------------------------------------------------
// K2b: merge splitS=2 partials (bf16 O, f32 l) -> Ab (4096 x 256 bf16).
// m=0 -> plain sums. 8 threads per q; each handles 4 d (8B bf16 loads).
// ---------------------------------------------------------------------------
__global__ __launch_bounds__(256) void combine_splits(
    const __hip_bfloat16* __restrict__ POb, const float* __restrict__ PL,
    __hip_bfloat16* __restrict__ Ab) {
  const int blk = blockIdx.x;                 // 1024 blocks: 64 per bh
  const int bh = blk >> 6;
  const int q = ((blk & 63) << 5) | (threadIdx.x >> 3);   // 32 q per block
  const int d4 = threadIdx.x & 7;             // 4-elem group within 32 d
  const int n = bh >> 3, h = bh & 7;
  float L = PL[(size_t)bh * 2048 + q] + PL[(size_t)(16 + bh) * 2048 + q];
  float inv = 1.f / L;
  union { ushort4 u; __hip_bfloat16 hh[4]; } a0, a1, o;
  a0.u = *(const ushort4*)&POb[((size_t)bh * 2048 + q) * 32 + d4 * 4];
  a1.u = *(const ushort4*)&POb[((size_t)(16 + bh) * 2048 + q) * 32 + d4 * 4];
#pragma unroll
  for (int i = 0; i < 4; ++i)
    o.hh[i] = __float2bfloat16((__bfloat162float(a0.hh[i]) +
                                __bfloat162float(a1.hh[i])) * inv);
  *(ushort4*)&Ab[((size_t)q * 2 + n) * 256 + h * 32 + d4 * 4] = o.u;
}

// ---------------------------------------------------------------------------
// K3: out projection, 64x64 tiles, all-bf16 staging (Wob pre-cast).
// out(4096 x 256, f32) = Ab @ Wob^T + bias
// ---------------------------------------------------------------------------
__global__ __launch_bounds__(256) void out_gemm(
    const __hip_bfloat16* __restrict__ A, const __hip_bfloat16* __restrict__ Wob,
    const float* __restrict__ bias, float* __restrict__ out) {
    __shared__ __hip_bfloat16 At[64][40];
    __shared__ __hip_bfloat16 Bt[64][40];
    const int tid = threadIdx.x;
    const int lane = tid & 63, w = tid >> 6;
    const int ln = lane & 15, kg = lane >> 4;
    const int wr = w >> 1, wc = w & 1;
    const int rowBase = blockIdx.y * 64;
    const int colBase = blockIdx.x * 64;
    float4v acc[2][2] = {};

    for (int kt = 0; kt < 8; ++kt) {
        int row = tid >> 2, c = tid & 3;
        *(short8b*)&At[row][c * 8] =
            *(const short8b*)&A[(size_t)(rowBase + row) * 256 + kt * 32 + c * 8];
        *(short8b*)&Bt[row][c * 8] =
            *(const short8b*)&Wob[(size_t)(colBase + row) * 256 + kt * 32 + c * 8];
        __syncthreads();
        short8b a[2], b[2];
#pragma unroll
        for (int mi = 0; mi < 2; ++mi) a[mi] = *(const short8b*)&At[wr * 32 + mi * 16 + ln][kg * 8];
#pragma unroll
        for (int nj = 0; nj < 2; ++nj) b[nj] = *(const short8b*)&Bt[wc * 32 + nj * 16 + ln][kg * 8];
#pragma unroll
        for (int mi = 0; mi < 2; ++mi)
#pragma unroll
            for (int nj = 0; nj < 2; ++nj)
                acc[mi][nj] = __builtin_amdgcn_mfma_f32_16x16x32_bf16(a[mi], b[nj], acc[mi][nj], 0, 0, 0);
        __syncthreads();
    }

#pragma unroll
    for (int mi = 0; mi < 2; ++mi) {
#pragma unroll
        for (int nj = 0; nj < 2; ++nj) {
            int j = colBase + wc * 32 + nj * 16 + ln;
            float bj = bias[j];
#pragma unroll
            for (int r = 0; r < 4; ++r) {
                int row = rowBase + wr * 32 + mi * 16 + kg * 4 + r;
                out[row * 256 + j] = acc[mi][nj][r] + bj;
            }
        }
    }
}

// ---------------------------------------------------------------------------
extern "C" void kernel_launch(void* const* d_in, const int* in_sizes, int n_in,
                              void* d_out, int out_size, void* d_ws, size_t ws_size,
                              hipStream_t stream) {
    const float* query = (const float*)d_in[0];
    const float* W_in  = (const float*)d_in[1];
    const float* b_in  = (const float*)d_in[2];
    const float* W_s   = (const float*)d_in[3];
    const float* b_s   = (const float*)d_in[4];
    const float* W_o   = (const float*)d_in[5];
    const float* b_o   = (const float*)d_in[6];
    const int*   qids  = (const int*)d_in[7];
    const int*   kids  = (const int*)d_in[8];
    float* out = (float*)d_out;

    __hip_bfloat16* Qs  = (__hip_bfloat16*)d_ws;       // [16][2048][32]
    __hip_bfloat16* Kg  = Qs + 16 * 2048 * 32;
    __hip_bfloat16* Vt  = Kg + 16 * 2048 * 32;         // [16][32][2048]
    __hip_bfloat16* Qf  = Vt + 16 * 2048 * 32;
    __hip_bfloat16* Kf  = Qf + 16 * 2048 * 32;
    __hip_bfloat16* Ab  = Kf + 16 * 2048 * 32;         // 4096 x 256
    __hip_bfloat16* Xb  = Ab + 4096 * 256;             // 4096 x 256
    __hip_bfloat16* Wbf = Xb + 4096 * 256;             // 1280 x 256
    __hip_bfloat16* Wob = Wbf + 1280 * 256;            // 256 x 256
    __hip_bfloat16* POb = Wob + 256 * 256;             // [2][16][2048][32] bf16
    float* PL = (float*)(POb + (size_t)2 * 16 * 2048 * 32);  // [2][16][2048] f32

    cast_all<<<1408, 256, 0, stream>>>(query, W_in, W_s, W_o, Xb, Wbf, Wob);
    proj_gemm<<<dim3(20, 32), 256, 0, stream>>>(Xb, Wbf, b_in, b_s,
                                                Qs, Kg, Vt, Qf, Kf);
    agent_attn<<<1024, 256, 0, stream>>>(Qs, Kg, Vt, Qf, Kf, qids, kids, POb, PL);
    combine_splits<<<1024, 256, 0, stream>>>(POb, PL, Ab);
    out_gemm<<<dim3(4, 64), 256, 0, stream>>>(Ab, Wob, b_o, out);
}